// Round 6
// baseline (1429.134 us; speedup 1.0000x reference)
//
#include <hip/hip_runtime.h>

// ---------------------------------------------------------------------------
// NaryCompUSchema: embed -> 3x masked LSTM (last hidden) -> segment_sum -> BPR
//   P[v, 0:1024]   = embed[v] @ col_W_ih^T + (col_b_ih + col_b_hh)   (bf16)
//   P[v,1024:2048] = embed[v] @ row_W_ih^T + (row_b_ih + row_b_hh)
//   Recurrence: gates^T = W_hh * h^T via mfma_f32_16x16x32_bf16.
// R6 (on R5's 16-wave structure, tau 23k cy decomposed):
//   - pstage layout conflict-free (was 4-way on every acc-init read, 17.1M
//     conflict cycles): gather lane=seq, [uh][seq][8] layout, 16B stride
//   - W loads: explicit 4-slot register ring, prefetch distance 2, full
//     unroll (addresses step-invariant; ring wraps across steps)
//   - P-DMA issued right after acc-init (whole kt loop to land)
//   - h pack via v_cvt_pk_bf16_f32 (2 instr instead of 16-op manual RNE)
// ---------------------------------------------------------------------------

typedef __bf16 bf16x8 __attribute__((ext_vector_type(8)));
typedef float  fvec4  __attribute__((ext_vector_type(4)));

#define NSEN 4096
#define HIDN 256
#define EMBD 300
#define VOC  50000

// workspace layout (bytes)
#define OFF_P     0ULL            // ushort [50000][2048]
#define OFF_WCAT  204800000ULL    // ushort [2048][320]   (ih weights, K padded)
#define OFF_WHHC  206110720ULL    // ushort [262144]      (packed frag order)
#define OFF_WHHR  206635008ULL    // ushort [262144]      (packed frag order)
#define OFF_BIAS  207159296ULL    // float  [2048]
#define OFF_H     207167488ULL    // float  [3][4096][256]
#define OFF_SEG   219750400ULL    // float  [3][4096][256]
#define OFF_LOSS  232333312ULL    // float  [4096]

static __device__ __forceinline__ unsigned short f2bf(float x) {
    unsigned int u = __float_as_uint(x);
    unsigned int r = (u + 0x7fffu + ((u >> 16) & 1u)) >> 16;  // RNE
    return (unsigned short)r;
}
static __device__ __forceinline__ float bf2f(unsigned short b) {
    return __uint_as_float(((unsigned int)b) << 16);
}
static __device__ __forceinline__ float sigm(float x) { return 1.f / (1.f + __expf(-x)); }
static __device__ __forceinline__ float tanh_(float x) {
    float e = __expf(2.f * x);
    return 1.f - 2.f / (e + 1.f);   // stable at +-inf
}
static __device__ __forceinline__ fvec4 unpk(uint2 v) {
    fvec4 o;
    o[0] = __uint_as_float((v.x & 0xffffu) << 16);
    o[1] = __uint_as_float(v.x & 0xffff0000u);
    o[2] = __uint_as_float((v.y & 0xffffu) << 16);
    o[3] = __uint_as_float(v.y & 0xffff0000u);
    return o;
}

// async 16B/lane gather into wave-private LDS (lane-ordered linear dest)
static __device__ __forceinline__ void gld_lds16(const unsigned short* g,
                                                 unsigned short* l)
{
    __builtin_amdgcn_global_load_lds(
        (const __attribute__((address_space(1))) unsigned int*)g,
        (__attribute__((address_space(3))) unsigned int*)l, 16, 0, 0);
}

// Whh packed layout (16-wave): frag L = (wv<<5)|(kt<<2)|g, elem = L*512+ln*8+j
// lane ln holds Whh[row][col], row = g*256 + wv*16 + (ln&15),
//                              col = kt*32 + (ln>>4)*8 + j
static __device__ __forceinline__ int whh_src(int o) {
    int L  = o >> 9;
    int r9 = o & 511;
    int ln = r9 >> 3, j = r9 & 7;
    int g  = L & 3, kt = (L >> 2) & 7, wv = (L >> 5) & 15;
    int row = g * 256 + wv * 16 + (ln & 15);
    int col = kt * 32 + (ln >> 4) * 8 + j;
    return row * 256 + col;
}

// ---------------------------------------------------------------- prep: pack
__global__ void prep_kernel(
    const float* __restrict__ cWih, const float* __restrict__ rWih,
    const float* __restrict__ cWhh, const float* __restrict__ rWhh,
    const float* __restrict__ cbih, const float* __restrict__ cbhh,
    const float* __restrict__ rbih, const float* __restrict__ rbhh,
    unsigned short* __restrict__ Wcat, unsigned short* __restrict__ WhhC,
    unsigned short* __restrict__ WhhR, float* __restrict__ biascat)
{
    int idx = blockIdx.x * 256 + threadIdx.x;
    if (idx < 2048 * 320) {
        int n = idx / 320, k = idx - n * 320;
        float v = 0.f;
        if (k < EMBD) v = (n < 1024) ? cWih[n * EMBD + k] : rWih[(n - 1024) * EMBD + k];
        Wcat[idx] = f2bf(v);
        return;
    }
    idx -= 2048 * 320;
    if (idx < 262144) { WhhC[idx] = f2bf(cWhh[whh_src(idx)]); return; }
    idx -= 262144;
    if (idx < 262144) { WhhR[idx] = f2bf(rWhh[whh_src(idx)]); return; }
    idx -= 262144;
    if (idx < 2048)
        biascat[idx] = (idx < 1024) ? (cbih[idx] + cbhh[idx])
                                    : (rbih[idx - 1024] + rbhh[idx - 1024]);
}

// ------------------------------------------------------- P = embed @ Wcat^T
__global__ __launch_bounds__(256) void gemm_p_kernel(
    const float* __restrict__ A,          // embed [50000][300] fp32
    const unsigned short* __restrict__ Bw,// Wcat  [2048][320] bf16
    const float* __restrict__ bias,       // [2048]
    unsigned short* __restrict__ Pout)    // [50000][2048] bf16
{
    const int nb = blockIdx.x * 128;
    const int mb = blockIdx.y * 128;
    const int tid = threadIdx.x;
    const int wv = tid >> 6, ln = tid & 63, l15 = ln & 15, q = ln >> 4;
    const int wm = wv & 1, wn = wv >> 1;

    __shared__ __align__(16) unsigned short At[128][40]; // [m][k] bf16, pad->40

    fvec4 acc[4][4];
    #pragma unroll
    for (int a = 0; a < 4; ++a)
        #pragma unroll
        for (int b = 0; b < 4; ++b) acc[a][b] = (fvec4)0.f;

    for (int kt = 0; kt < 10; ++kt) {
        const int K0 = kt * 32;
        __syncthreads();
        {
            int tr = tid >> 3;   // 0..31
            int tc = tid & 7;    // float4 column
            #pragma unroll
            for (int p = 0; p < 4; ++p) {
                int rrow = tr + p * 32;
                int gr = mb + rrow;
                float4 v = make_float4(0.f, 0.f, 0.f, 0.f);
                if (gr < VOC && (K0 + tc * 4) < EMBD)
                    v = *(const float4*)(A + (size_t)gr * EMBD + K0 + tc * 4);
                ushort4 b;
                b.x = f2bf(v.x); b.y = f2bf(v.y); b.z = f2bf(v.z); b.w = f2bf(v.w);
                *(ushort4*)&At[rrow][tc * 4] = b;
            }
        }
        __syncthreads();
        bf16x8 bf_[4];
        #pragma unroll
        for (int ntt = 0; ntt < 4; ++ntt) {
            int n = nb + wn * 64 + ntt * 16 + l15;
            bf_[ntt] = *(const bf16x8*)(Bw + (size_t)n * 320 + K0 + q * 8);
        }
        #pragma unroll
        for (int mt = 0; mt < 4; ++mt) {
            bf16x8 af = *(const bf16x8*)&At[wm * 64 + mt * 16 + l15][q * 8];
            #pragma unroll
            for (int ntt = 0; ntt < 4; ++ntt)
                acc[mt][ntt] = __builtin_amdgcn_mfma_f32_16x16x32_bf16(
                    af, bf_[ntt], acc[mt][ntt], 0, 0, 0);
        }
    }
    float bv[4];
    #pragma unroll
    for (int ntt = 0; ntt < 4; ++ntt) bv[ntt] = bias[nb + wn * 64 + ntt * 16 + l15];
    #pragma unroll
    for (int mt = 0; mt < 4; ++mt) {
        #pragma unroll
        for (int r = 0; r < 4; ++r) {
            int m = mb + wm * 64 + mt * 16 + q * 4 + r;
            if (m < VOC) {
                size_t base = (size_t)m * 2048 + nb + wn * 64;
                #pragma unroll
                for (int ntt = 0; ntt < 4; ++ntt)
                    Pout[base + ntt * 16 + l15] = f2bf(acc[mt][ntt][r] + bv[ntt]);
            }
        }
    }
}

// ----------------------------------------------------------------- LSTMs
// grid 384 x 1024: blocks [0,128) col, [128,256) row, [256,384) row_neg.
// Block: 32 seqs, 16 waves; wave wv owns hidden units [16wv, 16wv+16).
// W loads: 4-slot register ring, prefetch distance 2, full unroll.
// pstage [uh][seq][8] (conflict-free reads); DMA issued right after acc-init.
__global__ __launch_bounds__(1024, 4) void lstm_kernel(
    const int* __restrict__ colTok, const int* __restrict__ rowTok, const int* __restrict__ negTok,
    const int* __restrict__ colLen, const int* __restrict__ rowLen, const int* __restrict__ negLen,
    const unsigned short* __restrict__ P,
    const unsigned short* __restrict__ WhhC, const unsigned short* __restrict__ WhhR,
    float* __restrict__ Hout)
{
    const int part = blockIdx.x >> 7;
    const int sb = blockIdx.x & 127;
    const int s0 = sb * 32;
    const int* tok = part == 0 ? colTok : (part == 1 ? rowTok : negTok);
    const int* len = part == 0 ? colLen : (part == 1 ? rowLen : negLen);
    const unsigned short* Whh = part == 0 ? WhhC : WhhR;
    const int T = part == 0 ? 64 : 16;
    const int pco = part == 0 ? 0 : 1024;
    float* Ho = Hout + (size_t)part * (NSEN * HIDN);

    const int tid = threadIdx.x;
    const int wv = tid >> 6;            // 0..15
    const int ln = tid & 63, l15 = ln & 15, q = ln >> 4;
    const int sq32 = ln & 31, uh = ln >> 5;   // DMA gather mapping

    __shared__ __align__(16) unsigned short hbf[2][32][256];          // 32 KB
    __shared__ __align__(16) unsigned short pstage[16][4][2][32][8];  // 64 KB
    char* hB0 = (char*)&hbf[0][0][0];
    char* hB1 = (char*)&hbf[1][0][0];
    const int swz = (l15 & 7) << 4;     // XOR swizzle for h rows

    for (int i = tid; i < 2 * 32 * 256; i += 1024) (&hbf[0][0][0])[i] = 0;

    // lens in regs: per-lane loads + shfl-xor max over the 32 seqs
    const int len0 = len[s0 + l15];
    const int len1 = len[s0 + 16 + l15];
    int ml = max(len0, len1);
    #pragma unroll
    for (int off = 1; off < 16; off <<= 1) ml = max(ml, __shfl_xor(ml, off));
    const int maxlen = ml;

    // per-wave contiguous packed-Whh stream base (32 KB per wave per step)
    const unsigned short* wbase = Whh + (size_t)wv * 16384 + (size_t)ln * 8;

    float c[2][4];
    #pragma unroll
    for (int n = 0; n < 2; ++n)
        #pragma unroll
        for (int r = 0; r < 4; ++r) c[n][r] = 0.f;
    uint2 hpk[2];
    hpk[0] = make_uint2(0u, 0u);
    hpk[1] = make_uint2(0u, 0u);

    __syncthreads();   // hbf zero-init visible

    // ---- prologue: DMA-stage P rows for t=0.
    // lane l: seq = l&31, unit-half = l>>5 -> LDS [uh][seq][8] (lane-linear)
    {
        int tcur = tok[(s0 + sq32) * T];
        #pragma unroll
        for (int g = 0; g < 4; ++g) {
            const unsigned short* src =
                P + (size_t)tcur * 2048 + pco + g * 256 + wv * 16 + uh * 8;
            gld_lds16(src, &pstage[wv][g][0][0][0]);
        }
    }
    int tknext = tok[(s0 + sq32) * T + 1];   // T >= 16

    // ---- W register ring prologue: slots 0,1 <- kt 0,1
    bf16x8 wf[4][4];
    #pragma unroll
    for (int g = 0; g < 4; ++g) {
        wf[0][g] = *(const bf16x8*)(wbase + (size_t)(0 * 4 + g) * 512);
        wf[1][g] = *(const bf16x8*)(wbase + (size_t)(1 * 4 + g) * 512);
    }

    for (int t = 0; t < maxlen; ++t) {
        const char* hRd = (t & 1) ? hB1 : hB0;
        char* hWr = (t & 1) ? hB0 : hB1;

        // wait this wave's P-DMAs (issued last step) + any W stragglers
        asm volatile("s_waitcnt vmcnt(0)" ::: "memory");

        // acc init from staged P: [uh=q>>1][seq=nt*16+l15][(q&1)*4 + r]
        // (unit (q>>1)*8+(q&1)*4+r == q*4+r, matching the MFMA D layout)
        fvec4 acc[4][2];  // [gate][nt]
        #pragma unroll
        for (int g = 0; g < 4; ++g)
            #pragma unroll
            for (int nt = 0; nt < 2; ++nt)
                acc[g][nt] = unpk(*(const uint2*)
                    &pstage[wv][g][q >> 1][nt * 16 + l15][(q & 1) * 4]);

        // issue next step's DMAs NOW (whole kt loop to land). Guard: this
        // wave's pstage reads (just issued) must drain first.
        if (t + 1 < maxlen) {
            asm volatile("s_waitcnt lgkmcnt(0)" ::: "memory");
            __builtin_amdgcn_sched_barrier(0);
            #pragma unroll
            for (int g = 0; g < 4; ++g) {
                const unsigned short* src =
                    P + (size_t)tknext * 2048 + pco + g * 256 + wv * 16 + uh * 8;
                gld_lds16(src, &pstage[wv][g][0][0][0]);
            }
            int t2 = (t + 2 < T) ? (t + 2) : (T - 1);
            tknext = tok[(s0 + sq32) * T + t2];
        }

        // gates += Whh_slice * h^T ; W via 4-slot ring, prefetch distance 2.
        // Ring wraps across steps: (kt+2)&7 at kt=6,7 preloads next step's 0,1.
        #pragma unroll
        for (int kt = 0; kt < 8; ++kt) {
            const int ps = (kt + 2) & 3, pk = (kt + 2) & 7;
            #pragma unroll
            for (int g = 0; g < 4; ++g)
                wf[ps][g] = *(const bf16x8*)(wbase + (size_t)(pk * 4 + g) * 512);
            bf16x8 b0 = *(const bf16x8*)(hRd + l15 * 512 + ((kt * 64 + q * 16) ^ swz));
            bf16x8 b1 = *(const bf16x8*)(hRd + (16 + l15) * 512 + ((kt * 64 + q * 16) ^ swz));
            #pragma unroll
            for (int g = 0; g < 4; ++g) {
                acc[g][0] = __builtin_amdgcn_mfma_f32_16x16x32_bf16(wf[kt & 3][g], b0, acc[g][0], 0, 0, 0);
                acc[g][1] = __builtin_amdgcn_mfma_f32_16x16x32_bf16(wf[kt & 3][g], b1, acc[g][1], 0, 0, 0);
            }
        }

        // activation + h write to the other buffer (frozen lanes rewrite hpk)
        #pragma unroll
        for (int nt = 0; nt < 2; ++nt) {
            bool act = t < (nt ? len1 : len0);
            if (act) {
                float hr[4];
                #pragma unroll
                for (int r = 0; r < 4; ++r) {
                    float iv = acc[0][nt][r];
                    float fv = acc[1][nt][r];
                    float gv = acc[2][nt][r];
                    float ov = acc[3][nt][r];
                    float cn = sigm(fv) * c[nt][r] + sigm(iv) * tanh_(gv);
                    c[nt][r] = cn;
                    hr[r] = sigm(ov) * tanh_(cn);
                }
                unsigned int lo, hi;
                asm("v_cvt_pk_bf16_f32 %0, %1, %2" : "=v"(lo) : "v"(hr[0]), "v"(hr[1]));
                asm("v_cvt_pk_bf16_f32 %0, %1, %2" : "=v"(hi) : "v"(hr[2]), "v"(hr[3]));
                hpk[nt] = make_uint2(lo, hi);
            }
            *(uint2*)(hWr + (size_t)(nt * 16 + l15) * 512 +
                      ((wv * 32 + q * 8) ^ swz)) = hpk[nt];
        }
        // ONE barrier per step: h writes visible before next step's reads
        asm volatile("s_waitcnt lgkmcnt(0)\n\ts_barrier" ::: "memory");
    }

    const char* hF = (maxlen & 1) ? hB1 : hB0;
    for (int i = tid; i < 32 * HIDN; i += 1024) {
        int sq = i >> 8, hd = i & 255;
        unsigned short hv = *(const unsigned short*)
            (hF + (size_t)sq * 512 + ((hd * 2) ^ ((sq & 7) << 4)));
        Ho[(size_t)(s0 + sq) * HIDN + hd] = bf2f(hv);
    }
}

// ------------------------------------------------------------ segment sum
__global__ void scatter_kernel(const float* __restrict__ Hout,
                               const int* __restrict__ crefs, const int* __restrict__ rrefs,
                               const int* __restrict__ nrefs, float* __restrict__ seg)
{
    int idx = blockIdx.x * 256 + threadIdx.x;       // < 3 * 2^20
    int which = idx >> 20;
    int rem = idx & 1048575;
    int s = rem >> 8, hd = rem & 255;
    const int* refs = which == 0 ? crefs : (which == 1 ? rrefs : nrefs);
    int rf = refs[s];
    atomicAdd(&seg[(size_t)which * 1048576 + (size_t)rf * 256 + hd], Hout[idx]);
}

// ------------------------------------------------------------------ loss
__global__ void loss_kernel(const float* __restrict__ seg, float* __restrict__ part)
{
    int d = blockIdx.x, tid = threadIdx.x;
    const float* sc = seg + (size_t)d * 256;
    const float* sr = seg + 1048576 + (size_t)d * 256;
    const float* sn = seg + 2097152 + (size_t)d * 256;
    float a = sc[tid];
    float p = a * sr[tid];
    float n = a * sn[tid];
    for (int off = 32; off; off >>= 1) { p += __shfl_down(p, off); n += __shfl_down(n, off); }
    __shared__ float rp[4], rn[4];
    if ((tid & 63) == 0) { rp[tid >> 6] = p; rn[tid >> 6] = n; }
    __syncthreads();
    if (tid == 0) {
        float Ps = rp[0] + rp[1] + rp[2] + rp[3];
        float Ns = rn[0] + rn[1] + rn[2] + rn[3];
        float x = Ps - Ns;
        part[d] = fmaxf(-x, 0.f) + log1pf(expf(-fabsf(x)));  // softplus(-x)
    }
}

__global__ void reduce_kernel(const float* __restrict__ part, float* __restrict__ out)
{
    int tid = threadIdx.x;
    float s = 0.f;
    for (int i = tid; i < 4096; i += 256) s += part[i];
    for (int off = 32; off; off >>= 1) s += __shfl_down(s, off);
    __shared__ float r[4];
    if ((tid & 63) == 0) r[tid >> 6] = s;
    __syncthreads();
    if (tid == 0) out[0] = r[0] + r[1] + r[2] + r[3];
}

// ---------------------------------------------------------------------------
extern "C" void kernel_launch(void* const* d_in, const int* in_sizes, int n_in,
                              void* d_out, int out_size, void* d_ws, size_t ws_size,
                              hipStream_t stream)
{
    const int*   col      = (const int*)d_in[0];
    const int*   row      = (const int*)d_in[1];
    const int*   rneg     = (const int*)d_in[2];
    const int*   col_lens = (const int*)d_in[3];
    const int*   row_lens = (const int*)d_in[4];
    const int*   rng_lens = (const int*)d_in[5];
    const int*   col_refs = (const int*)d_in[6];
    const int*   row_refs = (const int*)d_in[7];
    const int*   rng_refs = (const int*)d_in[8];
    const float* embed    = (const float*)d_in[9];
    const float* cWih     = (const float*)d_in[10];
    const float* cWhh     = (const float*)d_in[11];
    const float* cbih     = (const float*)d_in[12];
    const float* cbhh     = (const float*)d_in[13];
    const float* rWih     = (const float*)d_in[14];
    const float* rWhh     = (const float*)d_in[15];
    const float* rbih     = (const float*)d_in[16];
    const float* rbhh     = (const float*)d_in[17];

    char* ws = (char*)d_ws;
    unsigned short* P    = (unsigned short*)(ws + OFF_P);
    unsigned short* Wcat = (unsigned short*)(ws + OFF_WCAT);
    unsigned short* WhhC = (unsigned short*)(ws + OFF_WHHC);
    unsigned short* WhhR = (unsigned short*)(ws + OFF_WHHR);
    float* biascat = (float*)(ws + OFF_BIAS);
    float* Hbuf    = (float*)(ws + OFF_H);
    float* seg     = (float*)(ws + OFF_SEG);
    float* lpart   = (float*)(ws + OFF_LOSS);

    hipMemsetAsync(seg, 0, 3 * 4096 * 256 * sizeof(float), stream);

    prep_kernel<<<4616, 256, 0, stream>>>(cWih, rWih, cWhh, rWhh,
                                          cbih, cbhh, rbih, rbhh,
                                          Wcat, WhhC, WhhR, biascat);
    gemm_p_kernel<<<dim3(16, 391), 256, 0, stream>>>(embed, Wcat, biascat, P);
    lstm_kernel<<<384, 1024, 0, stream>>>(col, row, rneg,
                                          col_lens, row_lens, rng_lens,
                                          P, WhhC, WhhR, Hbuf);
    scatter_kernel<<<12288, 256, 0, stream>>>(Hbuf, col_refs, row_refs, rng_refs, seg);
    loss_kernel<<<4096, 256, 0, stream>>>(seg, lpart);
    reduce_kernel<<<1, 256, 0, stream>>>(lpart, (float*)d_out);
}

// Round 7
// 1376.828 us; speedup vs baseline: 1.0380x; 1.0380x over previous
//
#include <hip/hip_runtime.h>

// ---------------------------------------------------------------------------
// NaryCompUSchema: embed -> 3x masked LSTM (last hidden) -> segment_sum -> BPR
//   P[v, 0:1024]   = embed[v] @ col_W_ih^T + (col_b_ih + col_b_hh)   (bf16)
//   P[v,1024:2048] = embed[v] @ row_W_ih^T + (row_b_ih + row_b_hh)
//   Recurrence: gates^T = W_hh * h^T via mfma_f32_16x16x32_bf16.
// R7 (R6 spilled: 4-slot W ring = 64 VGPR broke the 128 cap -> 57MB scratch):
//   - W ring shrunk to 2 slots (32 VGPR), distance 1, wraps across the
//     barrier (step starts with kt0 frags already in regs)
//   - h LDS layout k-major hx[buf][kt][nt][seq][qc][8]: a wave's 16 b128
//     reads each cover one contiguous 1KB region -> zero bank conflicts
//     (writes ~8-way but only 2/step); no XOR swizzle needed
//   - keeps R6's conflict-free pstage [uh][seq][8] + cvt_pk h-pack
// ---------------------------------------------------------------------------

typedef __bf16 bf16x8 __attribute__((ext_vector_type(8)));
typedef float  fvec4  __attribute__((ext_vector_type(4)));

#define NSEN 4096
#define HIDN 256
#define EMBD 300
#define VOC  50000

// workspace layout (bytes)
#define OFF_P     0ULL            // ushort [50000][2048]
#define OFF_WCAT  204800000ULL    // ushort [2048][320]   (ih weights, K padded)
#define OFF_WHHC  206110720ULL    // ushort [262144]      (packed frag order)
#define OFF_WHHR  206635008ULL    // ushort [262144]      (packed frag order)
#define OFF_BIAS  207159296ULL    // float  [2048]
#define OFF_H     207167488ULL    // float  [3][4096][256]
#define OFF_SEG   219750400ULL    // float  [3][4096][256]
#define OFF_LOSS  232333312ULL    // float  [4096]

static __device__ __forceinline__ unsigned short f2bf(float x) {
    unsigned int u = __float_as_uint(x);
    unsigned int r = (u + 0x7fffu + ((u >> 16) & 1u)) >> 16;  // RNE
    return (unsigned short)r;
}
static __device__ __forceinline__ float bf2f(unsigned short b) {
    return __uint_as_float(((unsigned int)b) << 16);
}
static __device__ __forceinline__ float sigm(float x) { return 1.f / (1.f + __expf(-x)); }
static __device__ __forceinline__ float tanh_(float x) {
    float e = __expf(2.f * x);
    return 1.f - 2.f / (e + 1.f);   // stable at +-inf
}
static __device__ __forceinline__ fvec4 unpk(uint2 v) {
    fvec4 o;
    o[0] = __uint_as_float((v.x & 0xffffu) << 16);
    o[1] = __uint_as_float(v.x & 0xffff0000u);
    o[2] = __uint_as_float((v.y & 0xffffu) << 16);
    o[3] = __uint_as_float(v.y & 0xffff0000u);
    return o;
}

// async 16B/lane gather into wave-private LDS (lane-ordered linear dest)
static __device__ __forceinline__ void gld_lds16(const unsigned short* g,
                                                 unsigned short* l)
{
    __builtin_amdgcn_global_load_lds(
        (const __attribute__((address_space(1))) unsigned int*)g,
        (__attribute__((address_space(3))) unsigned int*)l, 16, 0, 0);
}

// Whh packed layout (16-wave): frag L = (wv<<5)|(kt<<2)|g, elem = L*512+ln*8+j
// lane ln holds Whh[row][col], row = g*256 + wv*16 + (ln&15),
//                              col = kt*32 + (ln>>4)*8 + j
static __device__ __forceinline__ int whh_src(int o) {
    int L  = o >> 9;
    int r9 = o & 511;
    int ln = r9 >> 3, j = r9 & 7;
    int g  = L & 3, kt = (L >> 2) & 7, wv = (L >> 5) & 15;
    int row = g * 256 + wv * 16 + (ln & 15);
    int col = kt * 32 + (ln >> 4) * 8 + j;
    return row * 256 + col;
}

// ---------------------------------------------------------------- prep: pack
__global__ void prep_kernel(
    const float* __restrict__ cWih, const float* __restrict__ rWih,
    const float* __restrict__ cWhh, const float* __restrict__ rWhh,
    const float* __restrict__ cbih, const float* __restrict__ cbhh,
    const float* __restrict__ rbih, const float* __restrict__ rbhh,
    unsigned short* __restrict__ Wcat, unsigned short* __restrict__ WhhC,
    unsigned short* __restrict__ WhhR, float* __restrict__ biascat)
{
    int idx = blockIdx.x * 256 + threadIdx.x;
    if (idx < 2048 * 320) {
        int n = idx / 320, k = idx - n * 320;
        float v = 0.f;
        if (k < EMBD) v = (n < 1024) ? cWih[n * EMBD + k] : rWih[(n - 1024) * EMBD + k];
        Wcat[idx] = f2bf(v);
        return;
    }
    idx -= 2048 * 320;
    if (idx < 262144) { WhhC[idx] = f2bf(cWhh[whh_src(idx)]); return; }
    idx -= 262144;
    if (idx < 262144) { WhhR[idx] = f2bf(rWhh[whh_src(idx)]); return; }
    idx -= 262144;
    if (idx < 2048)
        biascat[idx] = (idx < 1024) ? (cbih[idx] + cbhh[idx])
                                    : (rbih[idx - 1024] + rbhh[idx - 1024]);
}

// ------------------------------------------------------- P = embed @ Wcat^T
__global__ __launch_bounds__(256) void gemm_p_kernel(
    const float* __restrict__ A,          // embed [50000][300] fp32
    const unsigned short* __restrict__ Bw,// Wcat  [2048][320] bf16
    const float* __restrict__ bias,       // [2048]
    unsigned short* __restrict__ Pout)    // [50000][2048] bf16
{
    const int nb = blockIdx.x * 128;
    const int mb = blockIdx.y * 128;
    const int tid = threadIdx.x;
    const int wv = tid >> 6, ln = tid & 63, l15 = ln & 15, q = ln >> 4;
    const int wm = wv & 1, wn = wv >> 1;

    __shared__ __align__(16) unsigned short At[128][40]; // [m][k] bf16, pad->40

    fvec4 acc[4][4];
    #pragma unroll
    for (int a = 0; a < 4; ++a)
        #pragma unroll
        for (int b = 0; b < 4; ++b) acc[a][b] = (fvec4)0.f;

    for (int kt = 0; kt < 10; ++kt) {
        const int K0 = kt * 32;
        __syncthreads();
        {
            int tr = tid >> 3;   // 0..31
            int tc = tid & 7;    // float4 column
            #pragma unroll
            for (int p = 0; p < 4; ++p) {
                int rrow = tr + p * 32;
                int gr = mb + rrow;
                float4 v = make_float4(0.f, 0.f, 0.f, 0.f);
                if (gr < VOC && (K0 + tc * 4) < EMBD)
                    v = *(const float4*)(A + (size_t)gr * EMBD + K0 + tc * 4);
                ushort4 b;
                b.x = f2bf(v.x); b.y = f2bf(v.y); b.z = f2bf(v.z); b.w = f2bf(v.w);
                *(ushort4*)&At[rrow][tc * 4] = b;
            }
        }
        __syncthreads();
        bf16x8 bf_[4];
        #pragma unroll
        for (int ntt = 0; ntt < 4; ++ntt) {
            int n = nb + wn * 64 + ntt * 16 + l15;
            bf_[ntt] = *(const bf16x8*)(Bw + (size_t)n * 320 + K0 + q * 8);
        }
        #pragma unroll
        for (int mt = 0; mt < 4; ++mt) {
            bf16x8 af = *(const bf16x8*)&At[wm * 64 + mt * 16 + l15][q * 8];
            #pragma unroll
            for (int ntt = 0; ntt < 4; ++ntt)
                acc[mt][ntt] = __builtin_amdgcn_mfma_f32_16x16x32_bf16(
                    af, bf_[ntt], acc[mt][ntt], 0, 0, 0);
        }
    }
    float bv[4];
    #pragma unroll
    for (int ntt = 0; ntt < 4; ++ntt) bv[ntt] = bias[nb + wn * 64 + ntt * 16 + l15];
    #pragma unroll
    for (int mt = 0; mt < 4; ++mt) {
        #pragma unroll
        for (int r = 0; r < 4; ++r) {
            int m = mb + wm * 64 + mt * 16 + q * 4 + r;
            if (m < VOC) {
                size_t base = (size_t)m * 2048 + nb + wn * 64;
                #pragma unroll
                for (int ntt = 0; ntt < 4; ++ntt)
                    Pout[base + ntt * 16 + l15] = f2bf(acc[mt][ntt][r] + bv[ntt]);
            }
        }
    }
}

// ----------------------------------------------------------------- LSTMs
// grid 384 x 1024: blocks [0,128) col, [128,256) row, [256,384) row_neg.
// Block: 32 seqs, 16 waves; wave wv owns hidden units [16wv, 16wv+16).
// h LDS k-major: hx[buf][kt][nt][seq16][qc4][8] -> conflict-free b128 reads.
// W via 2-slot register ring (32 VGPR), distance 1, wraps across barrier.
__global__ __launch_bounds__(1024, 4) void lstm_kernel(
    const int* __restrict__ colTok, const int* __restrict__ rowTok, const int* __restrict__ negTok,
    const int* __restrict__ colLen, const int* __restrict__ rowLen, const int* __restrict__ negLen,
    const unsigned short* __restrict__ P,
    const unsigned short* __restrict__ WhhC, const unsigned short* __restrict__ WhhR,
    float* __restrict__ Hout)
{
    const int part = blockIdx.x >> 7;
    const int sb = blockIdx.x & 127;
    const int s0 = sb * 32;
    const int* tok = part == 0 ? colTok : (part == 1 ? rowTok : negTok);
    const int* len = part == 0 ? colLen : (part == 1 ? rowLen : negLen);
    const unsigned short* Whh = part == 0 ? WhhC : WhhR;
    const int T = part == 0 ? 64 : 16;
    const int pco = part == 0 ? 0 : 1024;
    float* Ho = Hout + (size_t)part * (NSEN * HIDN);

    const int tid = threadIdx.x;
    const int wv = tid >> 6;            // 0..15
    const int ln = tid & 63, l15 = ln & 15, q = ln >> 4;
    const int sq32 = ln & 31, uh = ln >> 5;   // DMA gather mapping

    __shared__ __align__(16) unsigned short hx[2][8][2][16][4][8];    // 32 KB
    __shared__ __align__(16) unsigned short pstage[16][4][2][32][8];  // 64 KB
    char* hB0 = (char*)&hx[0][0][0][0][0][0];
    char* hB1 = (char*)&hx[1][0][0][0][0][0];

    for (int i = tid; i < 2 * 8192; i += 1024) (&hx[0][0][0][0][0][0])[i] = 0;

    // lens in regs: per-lane loads + shfl-xor max over the 32 seqs
    const int len0 = len[s0 + l15];
    const int len1 = len[s0 + 16 + l15];
    int ml = max(len0, len1);
    #pragma unroll
    for (int off = 1; off < 16; off <<= 1) ml = max(ml, __shfl_xor(ml, off));
    const int maxlen = ml;

    // per-wave contiguous packed-Whh stream base (32 KB per wave per step)
    const unsigned short* wbase = Whh + (size_t)wv * 16384 + (size_t)ln * 8;

    // h write address components (k-major layout):
    //   unit = wv*16 + q*4 + r -> kt' = wv>>1, qc = (wv&1)*2 + (q>>1),
    //   j = (q&1)*4 + r ; byte = kt'*2048 + nt*1024 + l15*64 + qc*16 + (q&1)*8
    const int wrByte = (wv >> 1) * 2048 + l15 * 64 +
                       ((wv & 1) * 2 + (q >> 1)) * 16 + (q & 1) * 8;

    float c[2][4];
    #pragma unroll
    for (int n = 0; n < 2; ++n)
        #pragma unroll
        for (int r = 0; r < 4; ++r) c[n][r] = 0.f;
    uint2 hpk[2];
    hpk[0] = make_uint2(0u, 0u);
    hpk[1] = make_uint2(0u, 0u);

    __syncthreads();   // hx zero-init visible

    // ---- prologue: DMA-stage P rows for t=0.
    // lane l: seq = l&31, unit-half = l>>5 -> LDS [uh][seq][8] (lane-linear)
    {
        int tcur = tok[(s0 + sq32) * T];
        #pragma unroll
        for (int g = 0; g < 4; ++g) {
            const unsigned short* src =
                P + (size_t)tcur * 2048 + pco + g * 256 + wv * 16 + uh * 8;
            gld_lds16(src, &pstage[wv][g][0][0][0]);
        }
    }
    int tknext = tok[(s0 + sq32) * T + 1];   // T >= 16

    // ---- W register ring prologue: slot 0 <- kt 0
    bf16x8 wf[2][4];
    #pragma unroll
    for (int g = 0; g < 4; ++g)
        wf[0][g] = *(const bf16x8*)(wbase + (size_t)(0 * 4 + g) * 512);

    for (int t = 0; t < maxlen; ++t) {
        const char* hRd = (t & 1) ? hB1 : hB0;
        char* hWr = (t & 1) ? hB0 : hB1;

        // wait this wave's P-DMAs (issued last step); W slot-0 frags for this
        // step were prefetched at kt=7 of the previous step (same addresses).
        asm volatile("s_waitcnt vmcnt(0)" ::: "memory");

        // acc init from staged P: [uh=q>>1][seq=nt*16+l15][(q&1)*4 + r]
        fvec4 acc[4][2];  // [gate][nt]
        #pragma unroll
        for (int g = 0; g < 4; ++g)
            #pragma unroll
            for (int nt = 0; nt < 2; ++nt)
                acc[g][nt] = unpk(*(const uint2*)
                    &pstage[wv][g][q >> 1][nt * 16 + l15][(q & 1) * 4]);

        // issue next step's DMAs NOW (whole kt loop to land). Guard: this
        // wave's pstage reads (just issued) must drain first.
        if (t + 1 < maxlen) {
            asm volatile("s_waitcnt lgkmcnt(0)" ::: "memory");
            __builtin_amdgcn_sched_barrier(0);
            #pragma unroll
            for (int g = 0; g < 4; ++g) {
                const unsigned short* src =
                    P + (size_t)tknext * 2048 + pco + g * 256 + wv * 16 + uh * 8;
                gld_lds16(src, &pstage[wv][g][0][0][0]);
            }
            int t2 = (t + 2 < T) ? (t + 2) : (T - 1);
            tknext = tok[(s0 + sq32) * T + t2];
        }

        // gates += Whh_slice * h^T; 2-slot ring: use wf[kt&1], prefetch
        // (kt+1)&7 into wf[(kt+1)&1]. kt=7 preloads next step's kt0.
        #pragma unroll
        for (int kt = 0; kt < 8; ++kt) {
            #pragma unroll
            for (int g = 0; g < 4; ++g)
                wf[(kt + 1) & 1][g] =
                    *(const bf16x8*)(wbase + (size_t)(((kt + 1) & 7) * 4 + g) * 512);
            // conflict-free h reads: contiguous 1KB region per (kt, nt)
            bf16x8 b0 = *(const bf16x8*)(hRd + kt * 2048 + l15 * 64 + q * 16);
            bf16x8 b1 = *(const bf16x8*)(hRd + kt * 2048 + 1024 + l15 * 64 + q * 16);
            #pragma unroll
            for (int g = 0; g < 4; ++g) {
                acc[g][0] = __builtin_amdgcn_mfma_f32_16x16x32_bf16(wf[kt & 1][g], b0, acc[g][0], 0, 0, 0);
                acc[g][1] = __builtin_amdgcn_mfma_f32_16x16x32_bf16(wf[kt & 1][g], b1, acc[g][1], 0, 0, 0);
            }
        }

        // activation + h write to the other buffer (frozen lanes rewrite hpk)
        #pragma unroll
        for (int nt = 0; nt < 2; ++nt) {
            bool act = t < (nt ? len1 : len0);
            if (act) {
                float hr[4];
                #pragma unroll
                for (int r = 0; r < 4; ++r) {
                    float iv = acc[0][nt][r];
                    float fv = acc[1][nt][r];
                    float gv = acc[2][nt][r];
                    float ov = acc[3][nt][r];
                    float cn = sigm(fv) * c[nt][r] + sigm(iv) * tanh_(gv);
                    c[nt][r] = cn;
                    hr[r] = sigm(ov) * tanh_(cn);
                }
                unsigned int lo, hi;
                asm("v_cvt_pk_bf16_f32 %0, %1, %2" : "=v"(lo) : "v"(hr[0]), "v"(hr[1]));
                asm("v_cvt_pk_bf16_f32 %0, %1, %2" : "=v"(hi) : "v"(hr[2]), "v"(hr[3]));
                hpk[nt] = make_uint2(lo, hi);
            }
            *(uint2*)(hWr + wrByte + nt * 1024) = hpk[nt];
        }
        // ONE barrier per step: h writes visible before next step's reads
        asm volatile("s_waitcnt lgkmcnt(0)\n\ts_barrier" ::: "memory");
    }

    const char* hF = (maxlen & 1) ? hB1 : hB0;
    for (int i = tid; i < 32 * HIDN; i += 1024) {
        int sq = i >> 8, hd = i & 255;
        unsigned short hv = *(const unsigned short*)
            (hF + (hd >> 5) * 2048 + (sq >> 4) * 1024 + (sq & 15) * 64 +
             ((hd >> 3) & 3) * 16 + (hd & 7) * 2);
        Ho[(size_t)(s0 + sq) * HIDN + hd] = bf2f(hv);
    }
}

// ------------------------------------------------------------ segment sum
__global__ void scatter_kernel(const float* __restrict__ Hout,
                               const int* __restrict__ crefs, const int* __restrict__ rrefs,
                               const int* __restrict__ nrefs, float* __restrict__ seg)
{
    int idx = blockIdx.x * 256 + threadIdx.x;       // < 3 * 2^20
    int which = idx >> 20;
    int rem = idx & 1048575;
    int s = rem >> 8, hd = rem & 255;
    const int* refs = which == 0 ? crefs : (which == 1 ? rrefs : nrefs);
    int rf = refs[s];
    atomicAdd(&seg[(size_t)which * 1048576 + (size_t)rf * 256 + hd], Hout[idx]);
}

// ------------------------------------------------------------------ loss
__global__ void loss_kernel(const float* __restrict__ seg, float* __restrict__ part)
{
    int d = blockIdx.x, tid = threadIdx.x;
    const float* sc = seg + (size_t)d * 256;
    const float* sr = seg + 1048576 + (size_t)d * 256;
    const float* sn = seg + 2097152 + (size_t)d * 256;
    float a = sc[tid];
    float p = a * sr[tid];
    float n = a * sn[tid];
    for (int off = 32; off; off >>= 1) { p += __shfl_down(p, off); n += __shfl_down(n, off); }
    __shared__ float rp[4], rn[4];
    if ((tid & 63) == 0) { rp[tid >> 6] = p; rn[tid >> 6] = n; }
    __syncthreads();
    if (tid == 0) {
        float Ps = rp[0] + rp[1] + rp[2] + rp[3];
        float Ns = rn[0] + rn[1] + rn[2] + rn[3];
        float x = Ps - Ns;
        part[d] = fmaxf(-x, 0.f) + log1pf(expf(-fabsf(x)));  // softplus(-x)
    }
}

__global__ void reduce_kernel(const float* __restrict__ part, float* __restrict__ out)
{
    int tid = threadIdx.x;
    float s = 0.f;
    for (int i = tid; i < 4096; i += 256) s += part[i];
    for (int off = 32; off; off >>= 1) s += __shfl_down(s, off);
    __shared__ float r[4];
    if ((tid & 63) == 0) r[tid >> 6] = s;
    __syncthreads();
    if (tid == 0) out[0] = r[0] + r[1] + r[2] + r[3];
}

// ---------------------------------------------------------------------------
extern "C" void kernel_launch(void* const* d_in, const int* in_sizes, int n_in,
                              void* d_out, int out_size, void* d_ws, size_t ws_size,
                              hipStream_t stream)
{
    const int*   col      = (const int*)d_in[0];
    const int*   row      = (const int*)d_in[1];
    const int*   rneg     = (const int*)d_in[2];
    const int*   col_lens = (const int*)d_in[3];
    const int*   row_lens = (const int*)d_in[4];
    const int*   rng_lens = (const int*)d_in[5];
    const int*   col_refs = (const int*)d_in[6];
    const int*   row_refs = (const int*)d_in[7];
    const int*   rng_refs = (const int*)d_in[8];
    const float* embed    = (const float*)d_in[9];
    const float* cWih     = (const float*)d_in[10];
    const float* cWhh     = (const float*)d_in[11];
    const float* cbih     = (const float*)d_in[12];
    const float* cbhh     = (const float*)d_in[13];
    const float* rWih     = (const float*)d_in[14];
    const float* rWhh     = (const float*)d_in[15];
    const float* rbih     = (const float*)d_in[16];
    const float* rbhh     = (const float*)d_in[17];

    char* ws = (char*)d_ws;
    unsigned short* P    = (unsigned short*)(ws + OFF_P);
    unsigned short* Wcat = (unsigned short*)(ws + OFF_WCAT);
    unsigned short* WhhC = (unsigned short*)(ws + OFF_WHHC);
    unsigned short* WhhR = (unsigned short*)(ws + OFF_WHHR);
    float* biascat = (float*)(ws + OFF_BIAS);
    float* Hbuf    = (float*)(ws + OFF_H);
    float* seg     = (float*)(ws + OFF_SEG);
    float* lpart   = (float*)(ws + OFF_LOSS);

    hipMemsetAsync(seg, 0, 3 * 4096 * 256 * sizeof(float), stream);

    prep_kernel<<<4616, 256, 0, stream>>>(cWih, rWih, cWhh, rWhh,
                                          cbih, cbhh, rbih, rbhh,
                                          Wcat, WhhC, WhhR, biascat);
    gemm_p_kernel<<<dim3(16, 391), 256, 0, stream>>>(embed, Wcat, biascat, P);
    lstm_kernel<<<384, 1024, 0, stream>>>(col, row, rneg,
                                          col_lens, row_lens, rng_lens,
                                          P, WhhC, WhhR, Hbuf);
    scatter_kernel<<<12288, 256, 0, stream>>>(Hbuf, col_refs, row_refs, rng_refs, seg);
    loss_kernel<<<4096, 256, 0, stream>>>(seg, lpart);
    reduce_kernel<<<1, 256, 0, stream>>>(lpart, (float*)d_out);
}

// Round 8
// 1172.439 us; speedup vs baseline: 1.2189x; 1.1743x over previous
//
#include <hip/hip_runtime.h>

// ---------------------------------------------------------------------------
// NaryCompUSchema: embed -> 3x masked LSTM (last hidden) -> segment_sum -> BPR
//   P[v, 0:1024]   = embed[v] @ col_W_ih^T + (col_b_ih + col_b_hh)   (bf16)
//   P[v,1024:2048] = embed[v] @ row_W_ih^T + (row_b_ih + row_b_hh)
//   Recurrence: gates^T = W_hh * h^T via mfma_f32_16x16x32_bf16.
// R8 = R5 structure (best: 620us, no spills) + register-free fixes only:
//   - NO explicit W register ring (R6/R7's ring spilled: +38-58MB scratch,
//     6:1 read:write excess = spilled value re-read per kt iteration).
//     Compiler-scheduled W loads, kt unroll 2, exactly as R5.
//   - pstage [wv][g][uh][seq][8]: conflict-free acc-init reads (R6 fix)
//   - h LDS region ordered [q][seq]: read byte = ln*16, perfectly lane-
//     linear -> zero bank conflict (R7's [seq][q] was 8-way, my error)
//   - cvt_pk_bf16_f32 h pack (2 instr vs 16-op manual RNE)
// ---------------------------------------------------------------------------

typedef __bf16 bf16x8 __attribute__((ext_vector_type(8)));
typedef float  fvec4  __attribute__((ext_vector_type(4)));

#define NSEN 4096
#define HIDN 256
#define EMBD 300
#define VOC  50000

// workspace layout (bytes)
#define OFF_P     0ULL            // ushort [50000][2048]
#define OFF_WCAT  204800000ULL    // ushort [2048][320]   (ih weights, K padded)
#define OFF_WHHC  206110720ULL    // ushort [262144]      (packed frag order)
#define OFF_WHHR  206635008ULL    // ushort [262144]      (packed frag order)
#define OFF_BIAS  207159296ULL    // float  [2048]
#define OFF_H     207167488ULL    // float  [3][4096][256]
#define OFF_SEG   219750400ULL    // float  [3][4096][256]
#define OFF_LOSS  232333312ULL    // float  [4096]

static __device__ __forceinline__ unsigned short f2bf(float x) {
    unsigned int u = __float_as_uint(x);
    unsigned int r = (u + 0x7fffu + ((u >> 16) & 1u)) >> 16;  // RNE
    return (unsigned short)r;
}
static __device__ __forceinline__ float bf2f(unsigned short b) {
    return __uint_as_float(((unsigned int)b) << 16);
}
static __device__ __forceinline__ float sigm(float x) { return 1.f / (1.f + __expf(-x)); }
static __device__ __forceinline__ float tanh_(float x) {
    float e = __expf(2.f * x);
    return 1.f - 2.f / (e + 1.f);   // stable at +-inf
}
static __device__ __forceinline__ fvec4 unpk(uint2 v) {
    fvec4 o;
    o[0] = __uint_as_float((v.x & 0xffffu) << 16);
    o[1] = __uint_as_float(v.x & 0xffff0000u);
    o[2] = __uint_as_float((v.y & 0xffffu) << 16);
    o[3] = __uint_as_float(v.y & 0xffff0000u);
    return o;
}

// async 16B/lane gather into wave-private LDS (lane-ordered linear dest)
static __device__ __forceinline__ void gld_lds16(const unsigned short* g,
                                                 unsigned short* l)
{
    __builtin_amdgcn_global_load_lds(
        (const __attribute__((address_space(1))) unsigned int*)g,
        (__attribute__((address_space(3))) unsigned int*)l, 16, 0, 0);
}

// Whh packed layout (16-wave): frag L = (wv<<5)|(kt<<2)|g, elem = L*512+ln*8+j
// lane ln holds Whh[row][col], row = g*256 + wv*16 + (ln&15),
//                              col = kt*32 + (ln>>4)*8 + j
static __device__ __forceinline__ int whh_src(int o) {
    int L  = o >> 9;
    int r9 = o & 511;
    int ln = r9 >> 3, j = r9 & 7;
    int g  = L & 3, kt = (L >> 2) & 7, wv = (L >> 5) & 15;
    int row = g * 256 + wv * 16 + (ln & 15);
    int col = kt * 32 + (ln >> 4) * 8 + j;
    return row * 256 + col;
}

// ---------------------------------------------------------------- prep: pack
__global__ void prep_kernel(
    const float* __restrict__ cWih, const float* __restrict__ rWih,
    const float* __restrict__ cWhh, const float* __restrict__ rWhh,
    const float* __restrict__ cbih, const float* __restrict__ cbhh,
    const float* __restrict__ rbih, const float* __restrict__ rbhh,
    unsigned short* __restrict__ Wcat, unsigned short* __restrict__ WhhC,
    unsigned short* __restrict__ WhhR, float* __restrict__ biascat)
{
    int idx = blockIdx.x * 256 + threadIdx.x;
    if (idx < 2048 * 320) {
        int n = idx / 320, k = idx - n * 320;
        float v = 0.f;
        if (k < EMBD) v = (n < 1024) ? cWih[n * EMBD + k] : rWih[(n - 1024) * EMBD + k];
        Wcat[idx] = f2bf(v);
        return;
    }
    idx -= 2048 * 320;
    if (idx < 262144) { WhhC[idx] = f2bf(cWhh[whh_src(idx)]); return; }
    idx -= 262144;
    if (idx < 262144) { WhhR[idx] = f2bf(rWhh[whh_src(idx)]); return; }
    idx -= 262144;
    if (idx < 2048)
        biascat[idx] = (idx < 1024) ? (cbih[idx] + cbhh[idx])
                                    : (rbih[idx - 1024] + rbhh[idx - 1024]);
}

// ------------------------------------------------------- P = embed @ Wcat^T
__global__ __launch_bounds__(256) void gemm_p_kernel(
    const float* __restrict__ A,          // embed [50000][300] fp32
    const unsigned short* __restrict__ Bw,// Wcat  [2048][320] bf16
    const float* __restrict__ bias,       // [2048]
    unsigned short* __restrict__ Pout)    // [50000][2048] bf16
{
    const int nb = blockIdx.x * 128;
    const int mb = blockIdx.y * 128;
    const int tid = threadIdx.x;
    const int wv = tid >> 6, ln = tid & 63, l15 = ln & 15, q = ln >> 4;
    const int wm = wv & 1, wn = wv >> 1;

    __shared__ __align__(16) unsigned short At[128][40]; // [m][k] bf16, pad->40

    fvec4 acc[4][4];
    #pragma unroll
    for (int a = 0; a < 4; ++a)
        #pragma unroll
        for (int b = 0; b < 4; ++b) acc[a][b] = (fvec4)0.f;

    for (int kt = 0; kt < 10; ++kt) {
        const int K0 = kt * 32;
        __syncthreads();
        {
            int tr = tid >> 3;   // 0..31
            int tc = tid & 7;    // float4 column
            #pragma unroll
            for (int p = 0; p < 4; ++p) {
                int rrow = tr + p * 32;
                int gr = mb + rrow;
                float4 v = make_float4(0.f, 0.f, 0.f, 0.f);
                if (gr < VOC && (K0 + tc * 4) < EMBD)
                    v = *(const float4*)(A + (size_t)gr * EMBD + K0 + tc * 4);
                ushort4 b;
                b.x = f2bf(v.x); b.y = f2bf(v.y); b.z = f2bf(v.z); b.w = f2bf(v.w);
                *(ushort4*)&At[rrow][tc * 4] = b;
            }
        }
        __syncthreads();
        bf16x8 bf_[4];
        #pragma unroll
        for (int ntt = 0; ntt < 4; ++ntt) {
            int n = nb + wn * 64 + ntt * 16 + l15;
            bf_[ntt] = *(const bf16x8*)(Bw + (size_t)n * 320 + K0 + q * 8);
        }
        #pragma unroll
        for (int mt = 0; mt < 4; ++mt) {
            bf16x8 af = *(const bf16x8*)&At[wm * 64 + mt * 16 + l15][q * 8];
            #pragma unroll
            for (int ntt = 0; ntt < 4; ++ntt)
                acc[mt][ntt] = __builtin_amdgcn_mfma_f32_16x16x32_bf16(
                    af, bf_[ntt], acc[mt][ntt], 0, 0, 0);
        }
    }
    float bv[4];
    #pragma unroll
    for (int ntt = 0; ntt < 4; ++ntt) bv[ntt] = bias[nb + wn * 64 + ntt * 16 + l15];
    #pragma unroll
    for (int mt = 0; mt < 4; ++mt) {
        #pragma unroll
        for (int r = 0; r < 4; ++r) {
            int m = mb + wm * 64 + mt * 16 + q * 4 + r;
            if (m < VOC) {
                size_t base = (size_t)m * 2048 + nb + wn * 64;
                #pragma unroll
                for (int ntt = 0; ntt < 4; ++ntt)
                    Pout[base + ntt * 16 + l15] = f2bf(acc[mt][ntt][r] + bv[ntt]);
            }
        }
    }
}

// ----------------------------------------------------------------- LSTMs
// grid 384 x 1024: blocks [0,128) col, [128,256) row, [256,384) row_neg.
// Block: 32 seqs, 16 waves; wave wv owns hidden units [16wv, 16wv+16).
// h LDS: hx[buf][kt][nt][q][seq16][8] -> read byte = ln*16 (zero conflict).
// W loads compiler-scheduled (kt unroll 2, R5 style -- no explicit ring).
__global__ __launch_bounds__(1024, 4) void lstm_kernel(
    const int* __restrict__ colTok, const int* __restrict__ rowTok, const int* __restrict__ negTok,
    const int* __restrict__ colLen, const int* __restrict__ rowLen, const int* __restrict__ negLen,
    const unsigned short* __restrict__ P,
    const unsigned short* __restrict__ WhhC, const unsigned short* __restrict__ WhhR,
    float* __restrict__ Hout)
{
    const int part = blockIdx.x >> 7;
    const int sb = blockIdx.x & 127;
    const int s0 = sb * 32;
    const int* tok = part == 0 ? colTok : (part == 1 ? rowTok : negTok);
    const int* len = part == 0 ? colLen : (part == 1 ? rowLen : negLen);
    const unsigned short* Whh = part == 0 ? WhhC : WhhR;
    const int T = part == 0 ? 64 : 16;
    const int pco = part == 0 ? 0 : 1024;
    float* Ho = Hout + (size_t)part * (NSEN * HIDN);

    const int tid = threadIdx.x;
    const int wv = tid >> 6;            // 0..15
    const int ln = tid & 63, l15 = ln & 15, q = ln >> 4;
    const int sq32 = ln & 31, uh = ln >> 5;   // DMA gather mapping

    __shared__ __align__(16) unsigned short hx[2][8][2][4][16][8];    // 32 KB
    __shared__ __align__(16) unsigned short pstage[16][4][2][32][8];  // 64 KB
    char* hB0 = (char*)&hx[0][0][0][0][0][0];
    char* hB1 = (char*)&hx[1][0][0][0][0][0];

    for (int i = tid; i < 16384; i += 1024) (&hx[0][0][0][0][0][0])[i] = 0;

    // lens in regs: per-lane loads + shfl-xor max over the 32 seqs
    const int len0 = len[s0 + l15];
    const int len1 = len[s0 + 16 + l15];
    int ml = max(len0, len1);
    #pragma unroll
    for (int off = 1; off < 16; off <<= 1) ml = max(ml, __shfl_xor(ml, off));
    const int maxlen = ml;

    // per-wave contiguous packed-Whh stream base (32 KB per wave per step)
    const unsigned short* wbase = Whh + (size_t)wv * 16384 + (size_t)ln * 8;

    // h write byte: unit = wv*16 + q*4 + r -> kt = wv>>1,
    // qc = (wv&1)*2 + (q>>1), j = (q&1)*4 + r
    const int wrByte = (wv >> 1) * 2048 + ((wv & 1) * 2 + (q >> 1)) * 256 +
                       l15 * 16 + (q & 1) * 8;

    float c[2][4];
    #pragma unroll
    for (int n = 0; n < 2; ++n)
        #pragma unroll
        for (int r = 0; r < 4; ++r) c[n][r] = 0.f;
    uint2 hpk[2];
    hpk[0] = make_uint2(0u, 0u);
    hpk[1] = make_uint2(0u, 0u);

    __syncthreads();   // hx zero-init visible

    // ---- prologue: DMA-stage P rows for t=0.
    // lane l: seq = l&31, unit-half = l>>5 -> LDS [uh][seq][8] (lane-linear)
    {
        int tcur = tok[(s0 + sq32) * T];
        #pragma unroll
        for (int g = 0; g < 4; ++g) {
            const unsigned short* src =
                P + (size_t)tcur * 2048 + pco + g * 256 + wv * 16 + uh * 8;
            gld_lds16(src, &pstage[wv][g][0][0][0]);
        }
    }
    int tknext = tok[(s0 + sq32) * T + 1];   // T >= 16

    for (int t = 0; t < maxlen; ++t) {
        const char* hRd = (t & 1) ? hB1 : hB0;
        char* hWr = (t & 1) ? hB0 : hB1;

        // wave-private: wait for this wave's stage DMAs (issued last step).
        // In-order vmcnt: DMAs precede last step's W loads, which were all
        // consumed by MFMA waits -> this is nearly free.
        asm volatile("s_waitcnt vmcnt(0)" ::: "memory");

        // acc init from staged P: [uh=q>>1][seq=nt*16+l15][(q&1)*4 + r]
        fvec4 acc[4][2];  // [gate][nt]
        #pragma unroll
        for (int g = 0; g < 4; ++g)
            #pragma unroll
            for (int nt = 0; nt < 2; ++nt)
                acc[g][nt] = unpk(*(const uint2*)
                    &pstage[wv][g][q >> 1][nt * 16 + l15][(q & 1) * 4]);

        // issue next step's DMAs NOW (whole kt loop to land). Guard: this
        // wave's pstage reads (just issued) must drain first.
        if (t + 1 < maxlen) {
            asm volatile("s_waitcnt lgkmcnt(0)" ::: "memory");
            __builtin_amdgcn_sched_barrier(0);
            #pragma unroll
            for (int g = 0; g < 4; ++g) {
                const unsigned short* src =
                    P + (size_t)tknext * 2048 + pco + g * 256 + wv * 16 + uh * 8;
                gld_lds16(src, &pstage[wv][g][0][0][0]);
            }
            int t2 = (t + 2 < T) ? (t + 2) : (T - 1);
            tknext = tok[(s0 + sq32) * T + t2];
        }

        // gates += Whh_slice * h^T  (contiguous packed frag stream, L2)
        // unroll 2: small body, compiler-scheduled load pipe (R5 proven)
        #pragma unroll 2
        for (int kt = 0; kt < 8; ++kt) {
            // zero-conflict h reads: byte = kt*2048 (+1024 for nt=1) + ln*16
            bf16x8 b0 = *(const bf16x8*)(hRd + kt * 2048 + ln * 16);
            bf16x8 b1 = *(const bf16x8*)(hRd + kt * 2048 + 1024 + ln * 16);
            #pragma unroll
            for (int g = 0; g < 4; ++g) {
                bf16x8 a = *(const bf16x8*)(wbase + (size_t)(kt * 4 + g) * 512);
                acc[g][0] = __builtin_amdgcn_mfma_f32_16x16x32_bf16(a, b0, acc[g][0], 0, 0, 0);
                acc[g][1] = __builtin_amdgcn_mfma_f32_16x16x32_bf16(a, b1, acc[g][1], 0, 0, 0);
            }
        }

        // activation + h write to the other buffer (frozen lanes rewrite hpk)
        #pragma unroll
        for (int nt = 0; nt < 2; ++nt) {
            bool act = t < (nt ? len1 : len0);
            if (act) {
                float hr[4];
                #pragma unroll
                for (int r = 0; r < 4; ++r) {
                    float iv = acc[0][nt][r];
                    float fv = acc[1][nt][r];
                    float gv = acc[2][nt][r];
                    float ov = acc[3][nt][r];
                    float cn = sigm(fv) * c[nt][r] + sigm(iv) * tanh_(gv);
                    c[nt][r] = cn;
                    hr[r] = sigm(ov) * tanh_(cn);
                }
                unsigned int lo, hi;
                asm("v_cvt_pk_bf16_f32 %0, %1, %2" : "=v"(lo) : "v"(hr[0]), "v"(hr[1]));
                asm("v_cvt_pk_bf16_f32 %0, %1, %2" : "=v"(hi) : "v"(hr[2]), "v"(hr[3]));
                hpk[nt] = make_uint2(lo, hi);
            }
            *(uint2*)(hWr + wrByte + nt * 1024) = hpk[nt];
        }
        // ONE barrier per step: h writes visible before next step's reads
        asm volatile("s_waitcnt lgkmcnt(0)\n\ts_barrier" ::: "memory");
    }

    const char* hF = (maxlen & 1) ? hB1 : hB0;
    for (int i = tid; i < 32 * HIDN; i += 1024) {
        int sq = i >> 8, hd = i & 255;
        unsigned short hv = *(const unsigned short*)
            (hF + (hd >> 5) * 2048 + (sq >> 4) * 1024 + ((hd >> 3) & 3) * 256 +
             (sq & 15) * 16 + (hd & 7) * 2);
        Ho[(size_t)(s0 + sq) * HIDN + hd] = bf2f(hv);
    }
}

// ------------------------------------------------------------ segment sum
__global__ void scatter_kernel(const float* __restrict__ Hout,
                               const int* __restrict__ crefs, const int* __restrict__ rrefs,
                               const int* __restrict__ nrefs, float* __restrict__ seg)
{
    int idx = blockIdx.x * 256 + threadIdx.x;       // < 3 * 2^20
    int which = idx >> 20;
    int rem = idx & 1048575;
    int s = rem >> 8, hd = rem & 255;
    const int* refs = which == 0 ? crefs : (which == 1 ? rrefs : nrefs);
    int rf = refs[s];
    atomicAdd(&seg[(size_t)which * 1048576 + (size_t)rf * 256 + hd], Hout[idx]);
}

// ------------------------------------------------------------------ loss
__global__ void loss_kernel(const float* __restrict__ seg, float* __restrict__ part)
{
    int d = blockIdx.x, tid = threadIdx.x;
    const float* sc = seg + (size_t)d * 256;
    const float* sr = seg + 1048576 + (size_t)d * 256;
    const float* sn = seg + 2097152 + (size_t)d * 256;
    float a = sc[tid];
    float p = a * sr[tid];
    float n = a * sn[tid];
    for (int off = 32; off; off >>= 1) { p += __shfl_down(p, off); n += __shfl_down(n, off); }
    __shared__ float rp[4], rn[4];
    if ((tid & 63) == 0) { rp[tid >> 6] = p; rn[tid >> 6] = n; }
    __syncthreads();
    if (tid == 0) {
        float Ps = rp[0] + rp[1] + rp[2] + rp[3];
        float Ns = rn[0] + rn[1] + rn[2] + rn[3];
        float x = Ps - Ns;
        part[d] = fmaxf(-x, 0.f) + log1pf(expf(-fabsf(x)));  // softplus(-x)
    }
}

__global__ void reduce_kernel(const float* __restrict__ part, float* __restrict__ out)
{
    int tid = threadIdx.x;
    float s = 0.f;
    for (int i = tid; i < 4096; i += 256) s += part[i];
    for (int off = 32; off; off >>= 1) s += __shfl_down(s, off);
    __shared__ float r[4];
    if ((tid & 63) == 0) r[tid >> 6] = s;
    __syncthreads();
    if (tid == 0) out[0] = r[0] + r[1] + r[2] + r[3];
}

// ---------------------------------------------------------------------------
extern "C" void kernel_launch(void* const* d_in, const int* in_sizes, int n_in,
                              void* d_out, int out_size, void* d_ws, size_t ws_size,
                              hipStream_t stream)
{
    const int*   col      = (const int*)d_in[0];
    const int*   row      = (const int*)d_in[1];
    const int*   rneg     = (const int*)d_in[2];
    const int*   col_lens = (const int*)d_in[3];
    const int*   row_lens = (const int*)d_in[4];
    const int*   rng_lens = (const int*)d_in[5];
    const int*   col_refs = (const int*)d_in[6];
    const int*   row_refs = (const int*)d_in[7];
    const int*   rng_refs = (const int*)d_in[8];
    const float* embed    = (const float*)d_in[9];
    const float* cWih     = (const float*)d_in[10];
    const float* cWhh     = (const float*)d_in[11];
    const float* cbih     = (const float*)d_in[12];
    const float* cbhh     = (const float*)d_in[13];
    const float* rWih     = (const float*)d_in[14];
    const float* rWhh     = (const float*)d_in[15];
    const float* rbih     = (const float*)d_in[16];
    const float* rbhh     = (const float*)d_in[17];

    char* ws = (char*)d_ws;
    unsigned short* P    = (unsigned short*)(ws + OFF_P);
    unsigned short* Wcat = (unsigned short*)(ws + OFF_WCAT);
    unsigned short* WhhC = (unsigned short*)(ws + OFF_WHHC);
    unsigned short* WhhR = (unsigned short*)(ws + OFF_WHHR);
    float* biascat = (float*)(ws + OFF_BIAS);
    float* Hbuf    = (float*)(ws + OFF_H);
    float* seg     = (float*)(ws + OFF_SEG);
    float* lpart   = (float*)(ws + OFF_LOSS);

    hipMemsetAsync(seg, 0, 3 * 4096 * 256 * sizeof(float), stream);

    prep_kernel<<<4616, 256, 0, stream>>>(cWih, rWih, cWhh, rWhh,
                                          cbih, cbhh, rbih, rbhh,
                                          Wcat, WhhC, WhhR, biascat);
    gemm_p_kernel<<<dim3(16, 391), 256, 0, stream>>>(embed, Wcat, biascat, P);
    lstm_kernel<<<384, 1024, 0, stream>>>(col, row, rneg,
                                          col_lens, row_lens, rng_lens,
                                          P, WhhC, WhhR, Hbuf);
    scatter_kernel<<<12288, 256, 0, stream>>>(Hbuf, col_refs, row_refs, rng_refs, seg);
    loss_kernel<<<4096, 256, 0, stream>>>(seg, lpart);
    reduce_kernel<<<1, 256, 0, stream>>>(lpart, (float*)d_out);
}

// Round 9
// 868.145 us; speedup vs baseline: 1.6462x; 1.3505x over previous
//
#include <hip/hip_runtime.h>

// ---------------------------------------------------------------------------
// NaryCompUSchema: embed -> 3x masked LSTM (last hidden) -> segment_sum -> BPR
//   P[v, 0:1024]   = embed[v] @ col_W_ih^T + (col_b_ih + col_b_hh)   (bf16)
//   P[v,1024:2048] = embed[v] @ row_W_ih^T + (row_b_ih + row_b_hh)
//   Recurrence: gates^T = W_hh * h^T via mfma_f32_16x16x32_bf16.
// R9:
//   lstm = R5 ordering (DMA issue AFTER kt loop, no pre-loop fence; manual
//   f2bf pack) + R8's conflict-free layouts (pstage [uh][seq][8], h k-major).
//   R8's regression (620->725) was the pre-kt-loop lgkmcnt+sched fence
//   (cold-start every step) + inline cvt_pk asm (m240).
//   gemm_p v3: one block = 128 M-rows x FULL N=2048. A slice staged once in
//   80KB LDS (bf16, fragment order, ln*16 reads) -> A read from HBM exactly
//   once (60MB, was ~1GB L3). B from prep-packed fragment streams (Bpk,
//   lane-contiguous 1KB/instr from L2, replaces Wcat; same bytes).
// ---------------------------------------------------------------------------

typedef __bf16 bf16x8 __attribute__((ext_vector_type(8)));
typedef float  fvec4  __attribute__((ext_vector_type(4)));

#define NSEN 4096
#define HIDN 256
#define EMBD 300
#define VOC  50000

// workspace layout (bytes)
#define OFF_P     0ULL            // ushort [50000][2048]
#define OFF_BPK   204800000ULL    // ushort [16][2][10][4][512]  (packed W_ih)
#define OFF_WHHC  206110720ULL    // ushort [262144]      (packed frag order)
#define OFF_WHHR  206635008ULL    // ushort [262144]      (packed frag order)
#define OFF_BIAS  207159296ULL    // float  [2048]
#define OFF_H     207167488ULL    // float  [3][4096][256]
#define OFF_SEG   219750400ULL    // float  [3][4096][256]
#define OFF_LOSS  232333312ULL    // float  [4096]

static __device__ __forceinline__ unsigned short f2bf(float x) {
    unsigned int u = __float_as_uint(x);
    unsigned int r = (u + 0x7fffu + ((u >> 16) & 1u)) >> 16;  // RNE
    return (unsigned short)r;
}
static __device__ __forceinline__ float bf2f(unsigned short b) {
    return __uint_as_float(((unsigned int)b) << 16);
}
static __device__ __forceinline__ float sigm(float x) { return 1.f / (1.f + __expf(-x)); }
static __device__ __forceinline__ float tanh_(float x) {
    float e = __expf(2.f * x);
    return 1.f - 2.f / (e + 1.f);   // stable at +-inf
}
static __device__ __forceinline__ fvec4 unpk(uint2 v) {
    fvec4 o;
    o[0] = __uint_as_float((v.x & 0xffffu) << 16);
    o[1] = __uint_as_float(v.x & 0xffff0000u);
    o[2] = __uint_as_float((v.y & 0xffffu) << 16);
    o[3] = __uint_as_float(v.y & 0xffff0000u);
    return o;
}

// async 16B/lane gather into wave-private LDS (lane-ordered linear dest)
static __device__ __forceinline__ void gld_lds16(const unsigned short* g,
                                                 unsigned short* l)
{
    __builtin_amdgcn_global_load_lds(
        (const __attribute__((address_space(1))) unsigned int*)g,
        (__attribute__((address_space(3))) unsigned int*)l, 16, 0, 0);
}

// Whh packed layout (16-wave): frag L = (wv<<5)|(kt<<2)|g, elem = L*512+ln*8+j
// lane ln holds Whh[row][col], row = g*256 + wv*16 + (ln&15),
//                              col = kt*32 + (ln>>4)*8 + j
static __device__ __forceinline__ int whh_src(int o) {
    int L  = o >> 9;
    int r9 = o & 511;
    int ln = r9 >> 3, j = r9 & 7;
    int g  = L & 3, kt = (L >> 2) & 7, wv = (L >> 5) & 15;
    int row = g * 256 + wv * 16 + (ln & 15);
    int col = kt * 32 + (ln >> 4) * 8 + j;
    return row * 256 + col;
}

// ---------------------------------------------------------------- prep: pack
__global__ void prep_kernel(
    const float* __restrict__ cWih, const float* __restrict__ rWih,
    const float* __restrict__ cWhh, const float* __restrict__ rWhh,
    const float* __restrict__ cbih, const float* __restrict__ cbhh,
    const float* __restrict__ rbih, const float* __restrict__ rbhh,
    unsigned short* __restrict__ Bpk, unsigned short* __restrict__ WhhC,
    unsigned short* __restrict__ WhhR, float* __restrict__ biascat)
{
    int idx = blockIdx.x * 256 + threadIdx.x;
    if (idx < 655360) {
        // Bpk: frag f = ((nc*2+wn)*10 + kt)*4 + ntt, elem e = ln*8 + j
        // lane ln holds Wih_cat[n][k], n = nc*128+wn*64+ntt*16+(ln&15),
        //                              k = kt*32+(ln>>4)*8+j
        int e = idx & 511, lnn = e >> 3, j = e & 7;
        int f = idx >> 9;
        int ntt = f & 3;
        int kc = f >> 2;            // (nc*2+wn)*10 + kt
        int kt = kc % 10;
        int s  = kc / 10;           // nc*2 + wn
        int n = (s >> 1) * 128 + (s & 1) * 64 + ntt * 16 + (lnn & 15);
        int k = kt * 32 + (lnn >> 4) * 8 + j;
        float v = 0.f;
        if (k < EMBD) v = (n < 1024) ? cWih[n * EMBD + k] : rWih[(n - 1024) * EMBD + k];
        Bpk[idx] = f2bf(v);
        return;
    }
    idx -= 655360;
    if (idx < 262144) { WhhC[idx] = f2bf(cWhh[whh_src(idx)]); return; }
    idx -= 262144;
    if (idx < 262144) { WhhR[idx] = f2bf(rWhh[whh_src(idx)]); return; }
    idx -= 262144;
    if (idx < 2048)
        biascat[idx] = (idx < 1024) ? (cbih[idx] + cbhh[idx])
                                    : (rbih[idx - 1024] + rbhh[idx - 1024]);
}

// ------------------------------------------------------- P = embed @ Wcat^T
// v3: grid 391; block owns 128 M-rows x full N=2048. A staged once in LDS.
__global__ __launch_bounds__(256) void gemm_p_kernel(
    const float* __restrict__ A,          // embed [50000][300] fp32
    const unsigned short* __restrict__ Bpk,
    const float* __restrict__ bias,       // [2048]
    unsigned short* __restrict__ Pout)    // [50000][2048] bf16
{
    const int mb = blockIdx.x * 128;
    const int tid = threadIdx.x;
    const int wv = tid >> 6, ln = tid & 63, l15 = ln & 15, q = ln >> 4;
    const int wm = wv & 1, wn = wv >> 1;

    // A frags: At[wm][mt][kt][512], elem = ln*8+j ; value A[row][k],
    // row = wm*64+mt*16+(ln&15), k = kt*32+(ln>>4)*8+j   (80 KB)
    __shared__ __align__(16) unsigned short At[2][4][10][512];

    {   // stage: thread t covers row = t>>1, k in [ (t&1)*160, +160 )
        int row = tid >> 1, kh = tid & 1;
        int gr = mb + row;
        unsigned short* dst = &At[row >> 6][(row >> 4) & 3][0][0];
        const int fl = row & 15;
        #pragma unroll
        for (int i = 0; i < 40; ++i) {
            int k = kh * 160 + i * 4;
            float4 v = make_float4(0.f, 0.f, 0.f, 0.f);
            if (gr < VOC && k < EMBD)
                v = *(const float4*)(A + (size_t)gr * EMBD + k);
            ushort4 b;
            b.x = f2bf(v.x); b.y = f2bf(v.y); b.z = f2bf(v.z); b.w = f2bf(v.w);
            int di = (k >> 5) * 512 + ((k >> 3) & 3) * 128 + fl * 8 + (k & 7);
            *(ushort4*)(dst + di) = b;
        }
    }
    __syncthreads();

    for (int nc = 0; nc < 16; ++nc) {
        fvec4 acc[4][4];
        #pragma unroll
        for (int a = 0; a < 4; ++a)
            #pragma unroll
            for (int b = 0; b < 4; ++b) acc[a][b] = (fvec4)0.f;

        #pragma unroll 2
        for (int kt = 0; kt < 10; ++kt) {
            const unsigned short* bp =
                Bpk + (size_t)(((nc * 2 + wn) * 10 + kt) * 4) * 512 + ln * 8;
            bf16x8 bfr[4];
            #pragma unroll
            for (int ntt = 0; ntt < 4; ++ntt)
                bfr[ntt] = *(const bf16x8*)(bp + ntt * 512);
            #pragma unroll
            for (int mt = 0; mt < 4; ++mt) {
                bf16x8 af = *(const bf16x8*)&At[wm][mt][kt][ln * 8];
                #pragma unroll
                for (int ntt = 0; ntt < 4; ++ntt)
                    acc[mt][ntt] = __builtin_amdgcn_mfma_f32_16x16x32_bf16(
                        af, bfr[ntt], acc[mt][ntt], 0, 0, 0);
            }
        }
        float bv[4];
        #pragma unroll
        for (int ntt = 0; ntt < 4; ++ntt)
            bv[ntt] = bias[nc * 128 + wn * 64 + ntt * 16 + l15];
        #pragma unroll
        for (int mt = 0; mt < 4; ++mt) {
            #pragma unroll
            for (int r = 0; r < 4; ++r) {
                int m = mb + wm * 64 + mt * 16 + q * 4 + r;
                if (m < VOC) {
                    size_t base = (size_t)m * 2048 + nc * 128 + wn * 64;
                    #pragma unroll
                    for (int ntt = 0; ntt < 4; ++ntt)
                        Pout[base + ntt * 16 + l15] = f2bf(acc[mt][ntt][r] + bv[ntt]);
                }
            }
        }
    }
}

// ----------------------------------------------------------------- LSTMs
// grid 384 x 1024: blocks [0,128) col, [128,256) row, [256,384) row_neg.
// Block: 32 seqs, 16 waves; wave wv owns hidden units [16wv, 16wv+16).
// R5 ordering (DMA after kt loop); R8 layouts (conflict-free).
__global__ __launch_bounds__(1024, 4) void lstm_kernel(
    const int* __restrict__ colTok, const int* __restrict__ rowTok, const int* __restrict__ negTok,
    const int* __restrict__ colLen, const int* __restrict__ rowLen, const int* __restrict__ negLen,
    const unsigned short* __restrict__ P,
    const unsigned short* __restrict__ WhhC, const unsigned short* __restrict__ WhhR,
    float* __restrict__ Hout)
{
    const int part = blockIdx.x >> 7;
    const int sb = blockIdx.x & 127;
    const int s0 = sb * 32;
    const int* tok = part == 0 ? colTok : (part == 1 ? rowTok : negTok);
    const int* len = part == 0 ? colLen : (part == 1 ? rowLen : negLen);
    const unsigned short* Whh = part == 0 ? WhhC : WhhR;
    const int T = part == 0 ? 64 : 16;
    const int pco = part == 0 ? 0 : 1024;
    float* Ho = Hout + (size_t)part * (NSEN * HIDN);

    const int tid = threadIdx.x;
    const int wv = tid >> 6;            // 0..15
    const int ln = tid & 63, l15 = ln & 15, q = ln >> 4;
    const int sq32 = ln & 31, uh = ln >> 5;   // DMA gather mapping

    __shared__ __align__(16) unsigned short hx[2][8][2][4][16][8];    // 32 KB
    __shared__ __align__(16) unsigned short pstage[16][4][2][32][8];  // 64 KB
    char* hB0 = (char*)&hx[0][0][0][0][0][0];
    char* hB1 = (char*)&hx[1][0][0][0][0][0];

    for (int i = tid; i < 16384; i += 1024) (&hx[0][0][0][0][0][0])[i] = 0;

    // lens in regs: per-lane loads + shfl-xor max over the 32 seqs
    const int len0 = len[s0 + l15];
    const int len1 = len[s0 + 16 + l15];
    int ml = max(len0, len1);
    #pragma unroll
    for (int off = 1; off < 16; off <<= 1) ml = max(ml, __shfl_xor(ml, off));
    const int maxlen = ml;

    // per-wave contiguous packed-Whh stream base (32 KB per wave per step)
    const unsigned short* wbase = Whh + (size_t)wv * 16384 + (size_t)ln * 8;

    // h write byte: unit = wv*16 + q*4 + r -> kt = wv>>1,
    // qc = (wv&1)*2 + (q>>1), j = (q&1)*4 + r
    const int wrByte = (wv >> 1) * 2048 + ((wv & 1) * 2 + (q >> 1)) * 256 +
                       l15 * 16 + (q & 1) * 8;

    float c[2][4];
    #pragma unroll
    for (int n = 0; n < 2; ++n)
        #pragma unroll
        for (int r = 0; r < 4; ++r) c[n][r] = 0.f;
    ushort4 hpk[2];
    hpk[0] = make_ushort4(0, 0, 0, 0);
    hpk[1] = make_ushort4(0, 0, 0, 0);

    __syncthreads();   // hx zero-init visible

    // ---- prologue: DMA-stage P rows for t=0.
    // lane l: seq = l&31, unit-half = l>>5 -> LDS [uh][seq][8] (lane-linear)
    {
        int tcur = tok[(s0 + sq32) * T];
        #pragma unroll
        for (int g = 0; g < 4; ++g) {
            const unsigned short* src =
                P + (size_t)tcur * 2048 + pco + g * 256 + wv * 16 + uh * 8;
            gld_lds16(src, &pstage[wv][g][0][0][0]);
        }
    }
    int tknext = tok[(s0 + sq32) * T + 1];   // T >= 16

    for (int t = 0; t < maxlen; ++t) {
        const char* hRd = (t & 1) ? hB1 : hB0;
        char* hWr = (t & 1) ? hB0 : hB1;

        // wave-private: wait for this wave's stage DMAs (issued last step)
        asm volatile("s_waitcnt vmcnt(0)" ::: "memory");

        // acc init from staged P: [uh=q>>1][seq=nt*16+l15][(q&1)*4 + r]
        fvec4 acc[4][2];  // [gate][nt]
        #pragma unroll
        for (int g = 0; g < 4; ++g)
            #pragma unroll
            for (int nt = 0; nt < 2; ++nt)
                acc[g][nt] = unpk(*(const uint2*)
                    &pstage[wv][g][q >> 1][nt * 16 + l15][(q & 1) * 4]);

        // gates += Whh_slice * h^T  (contiguous packed frag stream, L2)
        // unroll 2: small body, compiler-scheduled load pipe; W loads can
        // issue right after the vmcnt above, overlapping acc-init ds_reads.
        #pragma unroll 2
        for (int kt = 0; kt < 8; ++kt) {
            // zero-conflict h reads: byte = kt*2048 (+1024 for nt=1) + ln*16
            bf16x8 b0 = *(const bf16x8*)(hRd + kt * 2048 + ln * 16);
            bf16x8 b1 = *(const bf16x8*)(hRd + kt * 2048 + 1024 + ln * 16);
            #pragma unroll
            for (int g = 0; g < 4; ++g) {
                bf16x8 a = *(const bf16x8*)(wbase + (size_t)(kt * 4 + g) * 512);
                acc[g][0] = __builtin_amdgcn_mfma_f32_16x16x32_bf16(a, b0, acc[g][0], 0, 0, 0);
                acc[g][1] = __builtin_amdgcn_mfma_f32_16x16x32_bf16(a, b1, acc[g][1], 0, 0, 0);
            }
        }

        // issue next step's DMAs (wave-private pstage; this wave's pstage
        // ds_reads and h reads are complete -- lgkmcnt(0) guard, R5 order)
        if (t + 1 < maxlen) {
            __builtin_amdgcn_sched_barrier(0);
            asm volatile("s_waitcnt lgkmcnt(0)" ::: "memory");
            #pragma unroll
            for (int g = 0; g < 4; ++g) {
                const unsigned short* src =
                    P + (size_t)tknext * 2048 + pco + g * 256 + wv * 16 + uh * 8;
                gld_lds16(src, &pstage[wv][g][0][0][0]);
            }
            int t2 = (t + 2 < T) ? (t + 2) : (T - 1);
            tknext = tok[(s0 + sq32) * T + t2];
        }

        // activation + h write to the other buffer (frozen lanes rewrite hpk)
        #pragma unroll
        for (int nt = 0; nt < 2; ++nt) {
            bool act = t < (nt ? len1 : len0);
            if (act) {
                float hr[4];
                #pragma unroll
                for (int r = 0; r < 4; ++r) {
                    float iv = acc[0][nt][r];
                    float fv = acc[1][nt][r];
                    float gv = acc[2][nt][r];
                    float ov = acc[3][nt][r];
                    float cn = sigm(fv) * c[nt][r] + sigm(iv) * tanh_(gv);
                    c[nt][r] = cn;
                    hr[r] = sigm(ov) * tanh_(cn);
                }
                hpk[nt] = make_ushort4(f2bf(hr[0]), f2bf(hr[1]),
                                       f2bf(hr[2]), f2bf(hr[3]));
            }
            *(ushort4*)(hWr + wrByte + nt * 1024) = hpk[nt];
        }
        // ONE barrier per step: h writes visible before next step's reads
        asm volatile("s_waitcnt lgkmcnt(0)\n\ts_barrier" ::: "memory");
    }

    const char* hF = (maxlen & 1) ? hB1 : hB0;
    for (int i = tid; i < 32 * HIDN; i += 1024) {
        int sq = i >> 8, hd = i & 255;
        unsigned short hv = *(const unsigned short*)
            (hF + (hd >> 5) * 2048 + (sq >> 4) * 1024 + ((hd >> 3) & 3) * 256 +
             (sq & 15) * 16 + (hd & 7) * 2);
        Ho[(size_t)(s0 + sq) * HIDN + hd] = bf2f(hv);
    }
}

// ------------------------------------------------------------ segment sum
__global__ void scatter_kernel(const float* __restrict__ Hout,
                               const int* __restrict__ crefs, const int* __restrict__ rrefs,
                               const int* __restrict__ nrefs, float* __restrict__ seg)
{
    int idx = blockIdx.x * 256 + threadIdx.x;       // < 3 * 2^20
    int which = idx >> 20;
    int rem = idx & 1048575;
    int s = rem >> 8, hd = rem & 255;
    const int* refs = which == 0 ? crefs : (which == 1 ? rrefs : nrefs);
    int rf = refs[s];
    atomicAdd(&seg[(size_t)which * 1048576 + (size_t)rf * 256 + hd], Hout[idx]);
}

// ------------------------------------------------------------------ loss
__global__ void loss_kernel(const float* __restrict__ seg, float* __restrict__ part)
{
    int d = blockIdx.x, tid = threadIdx.x;
    const float* sc = seg + (size_t)d * 256;
    const float* sr = seg + 1048576 + (size_t)d * 256;
    const float* sn = seg + 2097152 + (size_t)d * 256;
    float a = sc[tid];
    float p = a * sr[tid];
    float n = a * sn[tid];
    for (int off = 32; off; off >>= 1) { p += __shfl_down(p, off); n += __shfl_down(n, off); }
    __shared__ float rp[4], rn[4];
    if ((tid & 63) == 0) { rp[tid >> 6] = p; rn[tid >> 6] = n; }
    __syncthreads();
    if (tid == 0) {
        float Ps = rp[0] + rp[1] + rp[2] + rp[3];
        float Ns = rn[0] + rn[1] + rn[2] + rn[3];
        float x = Ps - Ns;
        part[d] = fmaxf(-x, 0.f) + log1pf(expf(-fabsf(x)));  // softplus(-x)
    }
}

__global__ void reduce_kernel(const float* __restrict__ part, float* __restrict__ out)
{
    int tid = threadIdx.x;
    float s = 0.f;
    for (int i = tid; i < 4096; i += 256) s += part[i];
    for (int off = 32; off; off >>= 1) s += __shfl_down(s, off);
    __shared__ float r[4];
    if ((tid & 63) == 0) r[tid >> 6] = s;
    __syncthreads();
    if (tid == 0) out[0] = r[0] + r[1] + r[2] + r[3];
}

// ---------------------------------------------------------------------------
extern "C" void kernel_launch(void* const* d_in, const int* in_sizes, int n_in,
                              void* d_out, int out_size, void* d_ws, size_t ws_size,
                              hipStream_t stream)
{
    const int*   col      = (const int*)d_in[0];
    const int*   row      = (const int*)d_in[1];
    const int*   rneg     = (const int*)d_in[2];
    const int*   col_lens = (const int*)d_in[3];
    const int*   row_lens = (const int*)d_in[4];
    const int*   rng_lens = (const int*)d_in[5];
    const int*   col_refs = (const int*)d_in[6];
    const int*   row_refs = (const int*)d_in[7];
    const int*   rng_refs = (const int*)d_in[8];
    const float* embed    = (const float*)d_in[9];
    const float* cWih     = (const float*)d_in[10];
    const float* cWhh     = (const float*)d_in[11];
    const float* cbih     = (const float*)d_in[12];
    const float* cbhh     = (const float*)d_in[13];
    const float* rWih     = (const float*)d_in[14];
    const float* rWhh     = (const float*)d_in[15];
    const float* rbih     = (const float*)d_in[16];
    const float* rbhh     = (const float*)d_in[17];

    char* ws = (char*)d_ws;
    unsigned short* P    = (unsigned short*)(ws + OFF_P);
    unsigned short* Bpk  = (unsigned short*)(ws + OFF_BPK);
    unsigned short* WhhC = (unsigned short*)(ws + OFF_WHHC);
    unsigned short* WhhR = (unsigned short*)(ws + OFF_WHHR);
    float* biascat = (float*)(ws + OFF_BIAS);
    float* Hbuf    = (float*)(ws + OFF_H);
    float* seg     = (float*)(ws + OFF_SEG);
    float* lpart   = (float*)(ws + OFF_LOSS);

    hipMemsetAsync(seg, 0, 3 * 4096 * 256 * sizeof(float), stream);

    prep_kernel<<<4616, 256, 0, stream>>>(cWih, rWih, cWhh, rWhh,
                                          cbih, cbhh, rbih, rbhh,
                                          Bpk, WhhC, WhhR, biascat);
    gemm_p_kernel<<<391, 256, 0, stream>>>(embed, Bpk, biascat, P);
    lstm_kernel<<<384, 1024, 0, stream>>>(col, row, rneg,
                                          col_lens, row_lens, rng_lens,
                                          P, WhhC, WhhR, Hbuf);
    scatter_kernel<<<12288, 256, 0, stream>>>(Hbuf, col_refs, row_refs, rng_refs, seg);
    loss_kernel<<<4096, 256, 0, stream>>>(seg, lpart);
    reduce_kernel<<<1, 256, 0, stream>>>(lpart, (float*)d_out);
}

// Round 10
// 697.711 us; speedup vs baseline: 2.0483x; 1.2443x over previous
//
#include <hip/hip_runtime.h>

// ---------------------------------------------------------------------------
// NaryCompUSchema: embed -> 3x masked LSTM (last hidden) -> segment_sum -> BPR
//   P[v, 0:1024]   = embed[v] @ col_W_ih^T + (col_b_ih + col_b_hh)   (bf16)
//   P[v,1024:2048] = embed[v] @ row_W_ih^T + (row_b_ih + row_b_hh)
//   Recurrence: gates^T = W_hh * h^T via mfma_f32_16x16x32_bf16.
// R10: lstm tau is W-port-bound (512KB/step/CU from L2, ~9.4k cy floor,
// independent of seqs/block). Halve seqs/block 32->16: every other tau
// component halves (VALU, ds, MFMA, acc-init), col blocks double to 256
// -> one per CU in the tail (was 128, half the CUs idle).
//   - grid 768: col = blocks 0..255 (dispatched first), row, neg
//   - wave: 16 units x 16 seqs; acc 16 VGPR; 32 MFMA + 2 P-DMAs/step
//   - LDS 48KB (hx 16KB + pstage 32KB); launch_bounds(1024,2) (<=64 VGPR)
//   - W packed layout, gemm_p v3, all fragment mappings from verified R9
// ---------------------------------------------------------------------------

typedef __bf16 bf16x8 __attribute__((ext_vector_type(8)));
typedef float  fvec4  __attribute__((ext_vector_type(4)));

#define NSEN 4096
#define HIDN 256
#define EMBD 300
#define VOC  50000

// workspace layout (bytes)
#define OFF_P     0ULL            // ushort [50000][2048]
#define OFF_BPK   204800000ULL    // ushort [16][2][10][4][512]  (packed W_ih)
#define OFF_WHHC  206110720ULL    // ushort [262144]      (packed frag order)
#define OFF_WHHR  206635008ULL    // ushort [262144]      (packed frag order)
#define OFF_BIAS  207159296ULL    // float  [2048]
#define OFF_H     207167488ULL    // float  [3][4096][256]
#define OFF_SEG   219750400ULL    // float  [3][4096][256]
#define OFF_LOSS  232333312ULL    // float  [4096]

static __device__ __forceinline__ unsigned short f2bf(float x) {
    unsigned int u = __float_as_uint(x);
    unsigned int r = (u + 0x7fffu + ((u >> 16) & 1u)) >> 16;  // RNE
    return (unsigned short)r;
}
static __device__ __forceinline__ float bf2f(unsigned short b) {
    return __uint_as_float(((unsigned int)b) << 16);
}
static __device__ __forceinline__ float sigm(float x) { return 1.f / (1.f + __expf(-x)); }
static __device__ __forceinline__ float tanh_(float x) {
    float e = __expf(2.f * x);
    return 1.f - 2.f / (e + 1.f);   // stable at +-inf
}
static __device__ __forceinline__ fvec4 unpk(uint2 v) {
    fvec4 o;
    o[0] = __uint_as_float((v.x & 0xffffu) << 16);
    o[1] = __uint_as_float(v.x & 0xffff0000u);
    o[2] = __uint_as_float((v.y & 0xffffu) << 16);
    o[3] = __uint_as_float(v.y & 0xffff0000u);
    return o;
}

// async 16B/lane gather into wave-private LDS (lane-ordered linear dest)
static __device__ __forceinline__ void gld_lds16(const unsigned short* g,
                                                 unsigned short* l)
{
    __builtin_amdgcn_global_load_lds(
        (const __attribute__((address_space(1))) unsigned int*)g,
        (__attribute__((address_space(3))) unsigned int*)l, 16, 0, 0);
}

// Whh packed layout (16-wave): frag L = (wv<<5)|(kt<<2)|g, elem = L*512+ln*8+j
// lane ln holds Whh[row][col], row = g*256 + wv*16 + (ln&15),
//                              col = kt*32 + (ln>>4)*8 + j
static __device__ __forceinline__ int whh_src(int o) {
    int L  = o >> 9;
    int r9 = o & 511;
    int ln = r9 >> 3, j = r9 & 7;
    int g  = L & 3, kt = (L >> 2) & 7, wv = (L >> 5) & 15;
    int row = g * 256 + wv * 16 + (ln & 15);
    int col = kt * 32 + (ln >> 4) * 8 + j;
    return row * 256 + col;
}

// ---------------------------------------------------------------- prep: pack
__global__ void prep_kernel(
    const float* __restrict__ cWih, const float* __restrict__ rWih,
    const float* __restrict__ cWhh, const float* __restrict__ rWhh,
    const float* __restrict__ cbih, const float* __restrict__ cbhh,
    const float* __restrict__ rbih, const float* __restrict__ rbhh,
    unsigned short* __restrict__ Bpk, unsigned short* __restrict__ WhhC,
    unsigned short* __restrict__ WhhR, float* __restrict__ biascat)
{
    int idx = blockIdx.x * 256 + threadIdx.x;
    if (idx < 655360) {
        // Bpk: frag f = ((nc*2+wn)*10 + kt)*4 + ntt, elem e = ln*8 + j
        // lane ln holds Wih_cat[n][k], n = nc*128+wn*64+ntt*16+(ln&15),
        //                              k = kt*32+(ln>>4)*8+j
        int e = idx & 511, lnn = e >> 3, j = e & 7;
        int f = idx >> 9;
        int ntt = f & 3;
        int kc = f >> 2;            // (nc*2+wn)*10 + kt
        int kt = kc % 10;
        int s  = kc / 10;           // nc*2 + wn
        int n = (s >> 1) * 128 + (s & 1) * 64 + ntt * 16 + (lnn & 15);
        int k = kt * 32 + (lnn >> 4) * 8 + j;
        float v = 0.f;
        if (k < EMBD) v = (n < 1024) ? cWih[n * EMBD + k] : rWih[(n - 1024) * EMBD + k];
        Bpk[idx] = f2bf(v);
        return;
    }
    idx -= 655360;
    if (idx < 262144) { WhhC[idx] = f2bf(cWhh[whh_src(idx)]); return; }
    idx -= 262144;
    if (idx < 262144) { WhhR[idx] = f2bf(rWhh[whh_src(idx)]); return; }
    idx -= 262144;
    if (idx < 2048)
        biascat[idx] = (idx < 1024) ? (cbih[idx] + cbhh[idx])
                                    : (rbih[idx - 1024] + rbhh[idx - 1024]);
}

// ------------------------------------------------------- P = embed @ Wcat^T
// v3: grid 391; block owns 128 M-rows x full N=2048. A staged once in LDS.
__global__ __launch_bounds__(256) void gemm_p_kernel(
    const float* __restrict__ A,          // embed [50000][300] fp32
    const unsigned short* __restrict__ Bpk,
    const float* __restrict__ bias,       // [2048]
    unsigned short* __restrict__ Pout)    // [50000][2048] bf16
{
    const int mb = blockIdx.x * 128;
    const int tid = threadIdx.x;
    const int wv = tid >> 6, ln = tid & 63, l15 = ln & 15, q = ln >> 4;
    const int wm = wv & 1, wn = wv >> 1;

    // A frags: At[wm][mt][kt][512], elem = ln*8+j ; value A[row][k],
    // row = wm*64+mt*16+(ln&15), k = kt*32+(ln>>4)*8+j   (80 KB)
    __shared__ __align__(16) unsigned short At[2][4][10][512];

    {   // stage: thread t covers row = t>>1, k in [ (t&1)*160, +160 )
        int row = tid >> 1, kh = tid & 1;
        int gr = mb + row;
        unsigned short* dst = &At[row >> 6][(row >> 4) & 3][0][0];
        const int fl = row & 15;
        #pragma unroll
        for (int i = 0; i < 40; ++i) {
            int k = kh * 160 + i * 4;
            float4 v = make_float4(0.f, 0.f, 0.f, 0.f);
            if (gr < VOC && k < EMBD)
                v = *(const float4*)(A + (size_t)gr * EMBD + k);
            ushort4 b;
            b.x = f2bf(v.x); b.y = f2bf(v.y); b.z = f2bf(v.z); b.w = f2bf(v.w);
            int di = (k >> 5) * 512 + ((k >> 3) & 3) * 128 + fl * 8 + (k & 7);
            *(ushort4*)(dst + di) = b;
        }
    }
    __syncthreads();

    for (int nc = 0; nc < 16; ++nc) {
        fvec4 acc[4][4];
        #pragma unroll
        for (int a = 0; a < 4; ++a)
            #pragma unroll
            for (int b = 0; b < 4; ++b) acc[a][b] = (fvec4)0.f;

        #pragma unroll 2
        for (int kt = 0; kt < 10; ++kt) {
            const unsigned short* bp =
                Bpk + (size_t)(((nc * 2 + wn) * 10 + kt) * 4) * 512 + ln * 8;
            bf16x8 bfr[4];
            #pragma unroll
            for (int ntt = 0; ntt < 4; ++ntt)
                bfr[ntt] = *(const bf16x8*)(bp + ntt * 512);
            #pragma unroll
            for (int mt = 0; mt < 4; ++mt) {
                bf16x8 af = *(const bf16x8*)&At[wm][mt][kt][ln * 8];
                #pragma unroll
                for (int ntt = 0; ntt < 4; ++ntt)
                    acc[mt][ntt] = __builtin_amdgcn_mfma_f32_16x16x32_bf16(
                        af, bfr[ntt], acc[mt][ntt], 0, 0, 0);
            }
        }
        float bv[4];
        #pragma unroll
        for (int ntt = 0; ntt < 4; ++ntt)
            bv[ntt] = bias[nc * 128 + wn * 64 + ntt * 16 + l15];
        #pragma unroll
        for (int mt = 0; mt < 4; ++mt) {
            #pragma unroll
            for (int r = 0; r < 4; ++r) {
                int m = mb + wm * 64 + mt * 16 + q * 4 + r;
                if (m < VOC) {
                    size_t base = (size_t)m * 2048 + nc * 128 + wn * 64;
                    #pragma unroll
                    for (int ntt = 0; ntt < 4; ++ntt)
                        Pout[base + ntt * 16 + l15] = f2bf(acc[mt][ntt][r] + bv[ntt]);
                }
            }
        }
    }
}

// ----------------------------------------------------------------- LSTMs
// grid 768 x 1024: blocks [0,256) col, [256,512) row, [512,768) row_neg.
// Block: 16 seqs, 16 waves; wave wv owns hidden units [16wv, 16wv+16).
// Per wave per step: 32 W loads (32KB) + 2 P-DMAs + 1 token load; 32 MFMA.
// h LDS k-major hx[buf][kt][qc][seq][8]: read byte = ln*16 (zero conflict).
__global__ __launch_bounds__(1024, 2) void lstm_kernel(
    const int* __restrict__ colTok, const int* __restrict__ rowTok, const int* __restrict__ negTok,
    const int* __restrict__ colLen, const int* __restrict__ rowLen, const int* __restrict__ negLen,
    const unsigned short* __restrict__ P,
    const unsigned short* __restrict__ WhhC, const unsigned short* __restrict__ WhhR,
    float* __restrict__ Hout)
{
    const int part = blockIdx.x >> 8;
    const int sb = blockIdx.x & 255;
    const int s0 = sb * 16;
    const int* tok = part == 0 ? colTok : (part == 1 ? rowTok : negTok);
    const int* len = part == 0 ? colLen : (part == 1 ? rowLen : negLen);
    const unsigned short* Whh = part == 0 ? WhhC : WhhR;
    const int T = part == 0 ? 64 : 16;
    const int pco = part == 0 ? 0 : 1024;
    float* Ho = Hout + (size_t)part * (NSEN * HIDN);

    const int tid = threadIdx.x;
    const int wv = tid >> 6;            // 0..15
    const int ln = tid & 63, l15 = ln & 15, q = ln >> 4;

    __shared__ __align__(16) unsigned short hx[2][8][4][16][8];       // 16 KB
    __shared__ __align__(16) unsigned short pstage[16][4][2][16][8];  // 32 KB
    char* hB0 = (char*)&hx[0][0][0][0][0];
    char* hB1 = (char*)&hx[1][0][0][0][0];

    for (int i = tid; i < 8192; i += 1024) (&hx[0][0][0][0][0])[i] = 0;

    // lens in regs: per-lane load + shfl-xor max over the 16 seqs
    const int len0 = len[s0 + l15];
    int ml = len0;
    #pragma unroll
    for (int off = 1; off < 16; off <<= 1) ml = max(ml, __shfl_xor(ml, off));
    const int maxlen = ml;

    // per-wave contiguous packed-Whh stream base (32 KB per wave per step)
    const unsigned short* wbase = Whh + (size_t)wv * 16384 + (size_t)ln * 8;

    // h write byte: unit u = wv*16 + q*4 + r -> kt = wv>>1,
    // qc = (wv&1)*2 + (q>>1), j = (q&1)*4 + r ; seq = l15
    const int wrByte = (wv >> 1) * 1024 + ((wv & 1) * 2 + (q >> 1)) * 256 +
                       l15 * 16 + (q & 1) * 8;

    // DMA lane mapping: instr d stages gates 2d,2d+1 (1KB, dest lane-linear):
    // lane ln -> gate = 2d + (ln>>5), half = (ln>>4)&1, seq = ln&15
    const int dg = ln >> 5, dh = (ln >> 4) & 1;

    float c[4];
    #pragma unroll
    for (int r = 0; r < 4; ++r) c[r] = 0.f;
    ushort4 hpk = make_ushort4(0, 0, 0, 0);

    __syncthreads();   // hx zero-init visible

    // ---- prologue: DMA-stage P rows for t=0
    {
        int tk = tok[(s0 + l15) * T];
        #pragma unroll
        for (int d = 0; d < 2; ++d) {
            const unsigned short* src = P + (size_t)tk * 2048 + pco +
                (2 * d + dg) * 256 + wv * 16 + dh * 8;
            gld_lds16(src, &pstage[wv][2 * d][0][0][0]);
        }
    }
    int tknext = tok[(s0 + l15) * T + 1];   // T >= 16

    for (int t = 0; t < maxlen; ++t) {
        const char* hRd = (t & 1) ? hB1 : hB0;
        char* hWr = (t & 1) ? hB0 : hB1;

        // wave-private: wait for this wave's stage DMAs (issued last step)
        asm volatile("s_waitcnt vmcnt(0)" ::: "memory");

        // acc init from staged P: pstage[wv][g][q>>1][l15][(q&1)*4 + r]
        // (unit (q>>1)*8 + (q&1)*4 + r == q*4 + r, matching MFMA D layout)
        fvec4 acc[4];
        #pragma unroll
        for (int g = 0; g < 4; ++g)
            acc[g] = unpk(*(const uint2*)
                &pstage[wv][g][q >> 1][l15][(q & 1) * 4]);

        // gates += Whh_slice * h^T  (contiguous packed frag stream, L2)
        #pragma unroll 2
        for (int kt = 0; kt < 8; ++kt) {
            // zero-conflict h read: byte = kt*1024 + ln*16
            bf16x8 b0 = *(const bf16x8*)(hRd + kt * 1024 + ln * 16);
            #pragma unroll
            for (int g = 0; g < 4; ++g) {
                bf16x8 a = *(const bf16x8*)(wbase + (size_t)(kt * 4 + g) * 512);
                acc[g] = __builtin_amdgcn_mfma_f32_16x16x32_bf16(a, b0, acc[g], 0, 0, 0);
            }
        }

        // issue next step's DMAs (wave-private pstage; reads drained first)
        if (t + 1 < maxlen) {
            __builtin_amdgcn_sched_barrier(0);
            asm volatile("s_waitcnt lgkmcnt(0)" ::: "memory");
            #pragma unroll
            for (int d = 0; d < 2; ++d) {
                const unsigned short* src = P + (size_t)tknext * 2048 + pco +
                    (2 * d + dg) * 256 + wv * 16 + dh * 8;
                gld_lds16(src, &pstage[wv][2 * d][0][0][0]);
            }
            int t2 = (t + 2 < T) ? (t + 2) : (T - 1);
            tknext = tok[(s0 + l15) * T + t2];
        }

        // activation + h write to the other buffer (frozen lanes rewrite hpk)
        {
            bool act = t < len0;
            if (act) {
                float hr[4];
                #pragma unroll
                for (int r = 0; r < 4; ++r) {
                    float iv = acc[0][r];
                    float fv = acc[1][r];
                    float gv = acc[2][r];
                    float ov = acc[3][r];
                    float cn = sigm(fv) * c[r] + sigm(iv) * tanh_(gv);
                    c[r] = cn;
                    hr[r] = sigm(ov) * tanh_(cn);
                }
                hpk = make_ushort4(f2bf(hr[0]), f2bf(hr[1]),
                                   f2bf(hr[2]), f2bf(hr[3]));
            }
            *(ushort4*)(hWr + wrByte) = hpk;
        }
        // ONE barrier per step: h writes visible before next step's reads
        asm volatile("s_waitcnt lgkmcnt(0)\n\ts_barrier" ::: "memory");
    }

    const char* hF = (maxlen & 1) ? hB1 : hB0;
    for (int i = tid; i < 16 * HIDN; i += 1024) {
        int sq = i >> 8, hd = i & 255;
        unsigned short hv = *(const unsigned short*)
            (hF + (hd >> 5) * 1024 + ((hd >> 3) & 3) * 256 +
             sq * 16 + (hd & 7) * 2);
        Ho[(size_t)(s0 + sq) * HIDN + hd] = bf2f(hv);
    }
}

// ------------------------------------------------------------ segment sum
__global__ void scatter_kernel(const float* __restrict__ Hout,
                               const int* __restrict__ crefs, const int* __restrict__ rrefs,
                               const int* __restrict__ nrefs, float* __restrict__ seg)
{
    int idx = blockIdx.x * 256 + threadIdx.x;       // < 3 * 2^20
    int which = idx >> 20;
    int rem = idx & 1048575;
    int s = rem >> 8, hd = rem & 255;
    const int* refs = which == 0 ? crefs : (which == 1 ? rrefs : nrefs);
    int rf = refs[s];
    atomicAdd(&seg[(size_t)which * 1048576 + (size_t)rf * 256 + hd], Hout[idx]);
}

// ------------------------------------------------------------------ loss
__global__ void loss_kernel(const float* __restrict__ seg, float* __restrict__ part)
{
    int d = blockIdx.x, tid = threadIdx.x;
    const float* sc = seg + (size_t)d * 256;
    const float* sr = seg + 1048576 + (size_t)d * 256;
    const float* sn = seg + 2097152 + (size_t)d * 256;
    float a = sc[tid];
    float p = a * sr[tid];
    float n = a * sn[tid];
    for (int off = 32; off; off >>= 1) { p += __shfl_down(p, off); n += __shfl_down(n, off); }
    __shared__ float rp[4], rn[4];
    if ((tid & 63) == 0) { rp[tid >> 6] = p; rn[tid >> 6] = n; }
    __syncthreads();
    if (tid == 0) {
        float Ps = rp[0] + rp[1] + rp[2] + rp[3];
        float Ns = rn[0] + rn[1] + rn[2] + rn[3];
        float x = Ps - Ns;
        part[d] = fmaxf(-x, 0.f) + log1pf(expf(-fabsf(x)));  // softplus(-x)
    }
}

__global__ void reduce_kernel(const float* __restrict__ part, float* __restrict__ out)
{
    int tid = threadIdx.x;
    float s = 0.f;
    for (int i = tid; i < 4096; i += 256) s += part[i];
    for (int off = 32; off; off >>= 1) s += __shfl_down(s, off);
    __shared__ float r[4];
    if ((tid & 63) == 0) r[tid >> 6] = s;
    __syncthreads();
    if (tid == 0) out[0] = r[0] + r[1] + r[2] + r[3];
}

// ---------------------------------------------------------------------------
extern "C" void kernel_launch(void* const* d_in, const int* in_sizes, int n_in,
                              void* d_out, int out_size, void* d_ws, size_t ws_size,
                              hipStream_t stream)
{
    const int*   col      = (const int*)d_in[0];
    const int*   row      = (const int*)d_in[1];
    const int*   rneg     = (const int*)d_in[2];
    const int*   col_lens = (const int*)d_in[3];
    const int*   row_lens = (const int*)d_in[4];
    const int*   rng_lens = (const int*)d_in[5];
    const int*   col_refs = (const int*)d_in[6];
    const int*   row_refs = (const int*)d_in[7];
    const int*   rng_refs = (const int*)d_in[8];
    const float* embed    = (const float*)d_in[9];
    const float* cWih     = (const float*)d_in[10];
    const float* cWhh     = (const float*)d_in[11];
    const float* cbih     = (const float*)d_in[12];
    const float* cbhh     = (const float*)d_in[13];
    const float* rWih     = (const float*)d_in[14];
    const float* rWhh     = (const float*)d_in[15];
    const float* rbih     = (const float*)d_in[16];
    const float* rbhh     = (const float*)d_in[17];

    char* ws = (char*)d_ws;
    unsigned short* P    = (unsigned short*)(ws + OFF_P);
    unsigned short* Bpk  = (unsigned short*)(ws + OFF_BPK);
    unsigned short* WhhC = (unsigned short*)(ws + OFF_WHHC);
    unsigned short* WhhR = (unsigned short*)(ws + OFF_WHHR);
    float* biascat = (float*)(ws + OFF_BIAS);
    float* Hbuf    = (float*)(ws + OFF_H);
    float* seg     = (float*)(ws + OFF_SEG);
    float* lpart   = (float*)(ws + OFF_LOSS);

    hipMemsetAsync(seg, 0, 3 * 4096 * 256 * sizeof(float), stream);

    prep_kernel<<<4616, 256, 0, stream>>>(cWih, rWih, cWhh, rWhh,
                                          cbih, cbhh, rbih, rbhh,
                                          Bpk, WhhC, WhhR, biascat);
    gemm_p_kernel<<<391, 256, 0, stream>>>(embed, Bpk, biascat, P);
    lstm_kernel<<<768, 1024, 0, stream>>>(col, row, rneg,
                                          col_lens, row_lens, rng_lens,
                                          P, WhhC, WhhR, Hbuf);
    scatter_kernel<<<12288, 256, 0, stream>>>(Hbuf, col_refs, row_refs, rng_refs, seg);
    loss_kernel<<<4096, 256, 0, stream>>>(seg, lpart);
    reduce_kernel<<<1, 256, 0, stream>>>(lpart, (float*)d_out);
}

// Round 11
// 689.511 us; speedup vs baseline: 2.0727x; 1.0119x over previous
//
#include <hip/hip_runtime.h>

// ---------------------------------------------------------------------------
// NaryCompUSchema: embed -> 3x masked LSTM (last hidden) -> segment_sum -> BPR
//   P[v, 0:1024]   = embed[v] @ col_W_ih^T + (col_b_ih + col_b_hh)   (bf16)
//   P[v,1024:2048] = embed[v] @ row_W_ih^T + (row_b_ih + row_b_hh)
//   Recurrence: gates^T = W_hh * h^T via mfma_f32_16x16x32_bf16.
// R11 (lstm is L2-port-bound on the 512KB/step W stream; R10 wall =
// 16 contended + 48 solo steps = 374us floor, measured 452):
//   - FORCE 1 block/CU (LDS 81.5KB): col block 0 never shares its port ->
//     wall = 64 solo steps ~250us floor. Total block-steps (~16.5k) / 256
//     CUs ~ 64.5 = balanced; row/neg backfill CUs freed by short col blocks.
//   - pstage double-buffered (the extra 32KB IS the pad): drops the
//     lgkmcnt(0) guard before DMA re-issue (one less serial wait/step).
//   - scatter fused into lstm epilogue (atomicAdd into seg): kernel launch
//     + 25MB Hbuf write/read eliminated.
// ---------------------------------------------------------------------------

typedef __bf16 bf16x8 __attribute__((ext_vector_type(8)));
typedef float  fvec4  __attribute__((ext_vector_type(4)));

#define NSEN 4096
#define HIDN 256
#define EMBD 300
#define VOC  50000

// workspace layout (bytes)
#define OFF_P     0ULL            // ushort [50000][2048]
#define OFF_BPK   204800000ULL    // ushort [16][2][10][4][512]  (packed W_ih)
#define OFF_WHHC  206110720ULL    // ushort [262144]      (packed frag order)
#define OFF_WHHR  206635008ULL    // ushort [262144]      (packed frag order)
#define OFF_BIAS  207159296ULL    // float  [2048]
#define OFF_SEG   219750400ULL    // float  [3][4096][256]
#define OFF_LOSS  232333312ULL    // float  [4096]

static __device__ __forceinline__ unsigned short f2bf(float x) {
    unsigned int u = __float_as_uint(x);
    unsigned int r = (u + 0x7fffu + ((u >> 16) & 1u)) >> 16;  // RNE
    return (unsigned short)r;
}
static __device__ __forceinline__ float bf2f(unsigned short b) {
    return __uint_as_float(((unsigned int)b) << 16);
}
static __device__ __forceinline__ float sigm(float x) { return 1.f / (1.f + __expf(-x)); }
static __device__ __forceinline__ float tanh_(float x) {
    float e = __expf(2.f * x);
    return 1.f - 2.f / (e + 1.f);   // stable at +-inf
}
static __device__ __forceinline__ fvec4 unpk(uint2 v) {
    fvec4 o;
    o[0] = __uint_as_float((v.x & 0xffffu) << 16);
    o[1] = __uint_as_float(v.x & 0xffff0000u);
    o[2] = __uint_as_float((v.y & 0xffffu) << 16);
    o[3] = __uint_as_float(v.y & 0xffff0000u);
    return o;
}

// async 16B/lane gather into wave-private LDS (lane-ordered linear dest)
static __device__ __forceinline__ void gld_lds16(const unsigned short* g,
                                                 unsigned short* l)
{
    __builtin_amdgcn_global_load_lds(
        (const __attribute__((address_space(1))) unsigned int*)g,
        (__attribute__((address_space(3))) unsigned int*)l, 16, 0, 0);
}

// Whh packed layout (16-wave): frag L = (wv<<5)|(kt<<2)|g, elem = L*512+ln*8+j
// lane ln holds Whh[row][col], row = g*256 + wv*16 + (ln&15),
//                              col = kt*32 + (ln>>4)*8 + j
static __device__ __forceinline__ int whh_src(int o) {
    int L  = o >> 9;
    int r9 = o & 511;
    int ln = r9 >> 3, j = r9 & 7;
    int g  = L & 3, kt = (L >> 2) & 7, wv = (L >> 5) & 15;
    int row = g * 256 + wv * 16 + (ln & 15);
    int col = kt * 32 + (ln >> 4) * 8 + j;
    return row * 256 + col;
}

// ---------------------------------------------------------------- prep: pack
__global__ void prep_kernel(
    const float* __restrict__ cWih, const float* __restrict__ rWih,
    const float* __restrict__ cWhh, const float* __restrict__ rWhh,
    const float* __restrict__ cbih, const float* __restrict__ cbhh,
    const float* __restrict__ rbih, const float* __restrict__ rbhh,
    unsigned short* __restrict__ Bpk, unsigned short* __restrict__ WhhC,
    unsigned short* __restrict__ WhhR, float* __restrict__ biascat)
{
    int idx = blockIdx.x * 256 + threadIdx.x;
    if (idx < 655360) {
        // Bpk: frag f = ((nc*2+wn)*10 + kt)*4 + ntt, elem e = ln*8 + j
        // lane ln holds Wih_cat[n][k], n = nc*128+wn*64+ntt*16+(ln&15),
        //                              k = kt*32+(ln>>4)*8+j
        int e = idx & 511, lnn = e >> 3, j = e & 7;
        int f = idx >> 9;
        int ntt = f & 3;
        int kc = f >> 2;            // (nc*2+wn)*10 + kt
        int kt = kc % 10;
        int s  = kc / 10;           // nc*2 + wn
        int n = (s >> 1) * 128 + (s & 1) * 64 + ntt * 16 + (lnn & 15);
        int k = kt * 32 + (lnn >> 4) * 8 + j;
        float v = 0.f;
        if (k < EMBD) v = (n < 1024) ? cWih[n * EMBD + k] : rWih[(n - 1024) * EMBD + k];
        Bpk[idx] = f2bf(v);
        return;
    }
    idx -= 655360;
    if (idx < 262144) { WhhC[idx] = f2bf(cWhh[whh_src(idx)]); return; }
    idx -= 262144;
    if (idx < 262144) { WhhR[idx] = f2bf(rWhh[whh_src(idx)]); return; }
    idx -= 262144;
    if (idx < 2048)
        biascat[idx] = (idx < 1024) ? (cbih[idx] + cbhh[idx])
                                    : (rbih[idx - 1024] + rbhh[idx - 1024]);
}

// ------------------------------------------------------- P = embed @ Wcat^T
// v3: grid 391; block owns 128 M-rows x full N=2048. A staged once in LDS.
__global__ __launch_bounds__(256) void gemm_p_kernel(
    const float* __restrict__ A,          // embed [50000][300] fp32
    const unsigned short* __restrict__ Bpk,
    const float* __restrict__ bias,       // [2048]
    unsigned short* __restrict__ Pout)    // [50000][2048] bf16
{
    const int mb = blockIdx.x * 128;
    const int tid = threadIdx.x;
    const int wv = tid >> 6, ln = tid & 63, l15 = ln & 15, q = ln >> 4;
    const int wm = wv & 1, wn = wv >> 1;

    // A frags: At[wm][mt][kt][512], elem = ln*8+j ; value A[row][k],
    // row = wm*64+mt*16+(ln&15), k = kt*32+(ln>>4)*8+j   (80 KB)
    __shared__ __align__(16) unsigned short At[2][4][10][512];

    {   // stage: thread t covers row = t>>1, k in [ (t&1)*160, +160 )
        int row = tid >> 1, kh = tid & 1;
        int gr = mb + row;
        unsigned short* dst = &At[row >> 6][(row >> 4) & 3][0][0];
        const int fl = row & 15;
        #pragma unroll
        for (int i = 0; i < 40; ++i) {
            int k = kh * 160 + i * 4;
            float4 v = make_float4(0.f, 0.f, 0.f, 0.f);
            if (gr < VOC && k < EMBD)
                v = *(const float4*)(A + (size_t)gr * EMBD + k);
            ushort4 b;
            b.x = f2bf(v.x); b.y = f2bf(v.y); b.z = f2bf(v.z); b.w = f2bf(v.w);
            int di = (k >> 5) * 512 + ((k >> 3) & 3) * 128 + fl * 8 + (k & 7);
            *(ushort4*)(dst + di) = b;
        }
    }
    __syncthreads();

    for (int nc = 0; nc < 16; ++nc) {
        fvec4 acc[4][4];
        #pragma unroll
        for (int a = 0; a < 4; ++a)
            #pragma unroll
            for (int b = 0; b < 4; ++b) acc[a][b] = (fvec4)0.f;

        #pragma unroll 2
        for (int kt = 0; kt < 10; ++kt) {
            const unsigned short* bp =
                Bpk + (size_t)(((nc * 2 + wn) * 10 + kt) * 4) * 512 + ln * 8;
            bf16x8 bfr[4];
            #pragma unroll
            for (int ntt = 0; ntt < 4; ++ntt)
                bfr[ntt] = *(const bf16x8*)(bp + ntt * 512);
            #pragma unroll
            for (int mt = 0; mt < 4; ++mt) {
                bf16x8 af = *(const bf16x8*)&At[wm][mt][kt][ln * 8];
                #pragma unroll
                for (int ntt = 0; ntt < 4; ++ntt)
                    acc[mt][ntt] = __builtin_amdgcn_mfma_f32_16x16x32_bf16(
                        af, bfr[ntt], acc[mt][ntt], 0, 0, 0);
            }
        }
        float bv[4];
        #pragma unroll
        for (int ntt = 0; ntt < 4; ++ntt)
            bv[ntt] = bias[nc * 128 + wn * 64 + ntt * 16 + l15];
        #pragma unroll
        for (int mt = 0; mt < 4; ++mt) {
            #pragma unroll
            for (int r = 0; r < 4; ++r) {
                int m = mb + wm * 64 + mt * 16 + q * 4 + r;
                if (m < VOC) {
                    size_t base = (size_t)m * 2048 + nc * 128 + wn * 64;
                    #pragma unroll
                    for (int ntt = 0; ntt < 4; ++ntt)
                        Pout[base + ntt * 16 + l15] = f2bf(acc[mt][ntt][r] + bv[ntt]);
                }
            }
        }
    }
}

// ----------------------------------------------------------------- LSTMs
// grid 768 x 1024: blocks [0,256) col, [256,512) row, [512,768) row_neg.
// Block: 16 seqs, 16 waves; wave wv owns hidden units [16wv, 16wv+16).
// LDS 81.5KB -> exactly 1 block/CU: critical col block never shares its
// L2 port. pstage double-buffered (no lgkm guard before DMA re-issue).
// Epilogue: fused segment-sum (atomicAdd into seg).
__global__ __launch_bounds__(1024, 2) void lstm_kernel(
    const int* __restrict__ colTok, const int* __restrict__ rowTok, const int* __restrict__ negTok,
    const int* __restrict__ colLen, const int* __restrict__ rowLen, const int* __restrict__ negLen,
    const int* __restrict__ crefs, const int* __restrict__ rrefs, const int* __restrict__ nrefs,
    const unsigned short* __restrict__ P,
    const unsigned short* __restrict__ WhhC, const unsigned short* __restrict__ WhhR,
    float* __restrict__ seg)
{
    const int part = blockIdx.x >> 8;
    const int sb = blockIdx.x & 255;
    const int s0 = sb * 16;
    const int* tok = part == 0 ? colTok : (part == 1 ? rowTok : negTok);
    const int* len = part == 0 ? colLen : (part == 1 ? rowLen : negLen);
    const int* refs = part == 0 ? crefs : (part == 1 ? rrefs : nrefs);
    const unsigned short* Whh = part == 0 ? WhhC : WhhR;
    const int T = part == 0 ? 64 : 16;
    const int pco = part == 0 ? 0 : 1024;
    float* segp = seg + (size_t)part * 1048576;

    const int tid = threadIdx.x;
    const int wv = tid >> 6;            // 0..15
    const int ln = tid & 63, l15 = ln & 15, q = ln >> 4;

    __shared__ __align__(16) unsigned short hx[2][8][4][16][8];          // 16 KB
    __shared__ __align__(16) unsigned short pstage[2][16][4][2][16][8];  // 64 KB
    __shared__ __align__(16) char ldspad[1536];  // force 1 block/CU (>80 KB)
    char* hB0 = (char*)&hx[0][0][0][0][0];
    char* hB1 = (char*)&hx[1][0][0][0][0];

    for (int i = tid; i < 8192; i += 1024) (&hx[0][0][0][0][0])[i] = 0;

    // lens in regs: per-lane load + shfl-xor max over the 16 seqs
    const int len0 = len[s0 + l15];
    int ml = len0;
    #pragma unroll
    for (int off = 1; off < 16; off <<= 1) ml = max(ml, __shfl_xor(ml, off));
    const int maxlen = ml;
    if (maxlen < 0) ldspad[tid & 1023] = 1;   // never true; keeps pad alive

    // per-wave contiguous packed-Whh stream base (32 KB per wave per step)
    const unsigned short* wbase = Whh + (size_t)wv * 16384 + (size_t)ln * 8;

    // h write byte: unit u = wv*16 + q*4 + r -> kt = wv>>1,
    // qc = (wv&1)*2 + (q>>1), j = (q&1)*4 + r ; seq = l15
    const int wrByte = (wv >> 1) * 1024 + ((wv & 1) * 2 + (q >> 1)) * 256 +
                       l15 * 16 + (q & 1) * 8;

    // DMA lane mapping: instr d stages gates 2d,2d+1 (1KB, dest lane-linear):
    // lane ln -> gate = 2d + (ln>>5), half = (ln>>4)&1, seq = ln&15
    const int dg = ln >> 5, dh = (ln >> 4) & 1;

    float c[4];
    #pragma unroll
    for (int r = 0; r < 4; ++r) c[r] = 0.f;
    ushort4 hpk = make_ushort4(0, 0, 0, 0);

    __syncthreads();   // hx zero-init visible

    // ---- prologue: DMA-stage P rows for t=0 into pstage[0]
    {
        int tk = tok[(s0 + l15) * T];
        #pragma unroll
        for (int d = 0; d < 2; ++d) {
            const unsigned short* src = P + (size_t)tk * 2048 + pco +
                (2 * d + dg) * 256 + wv * 16 + dh * 8;
            gld_lds16(src, &pstage[0][wv][2 * d][0][0][0]);
        }
    }
    int tknext = tok[(s0 + l15) * T + 1];   // T >= 16

    for (int t = 0; t < maxlen; ++t) {
        const int pb = t & 1;
        const char* hRd = (t & 1) ? hB1 : hB0;
        char* hWr = (t & 1) ? hB0 : hB1;

        // wave-private: wait for this wave's stage DMAs (issued last step)
        asm volatile("s_waitcnt vmcnt(0)" ::: "memory");

        // acc init from staged P: pstage[pb][wv][g][q>>1][l15][(q&1)*4 + r]
        fvec4 acc[4];
        #pragma unroll
        for (int g = 0; g < 4; ++g)
            acc[g] = unpk(*(const uint2*)
                &pstage[pb][wv][g][q >> 1][l15][(q & 1) * 4]);

        // gates += Whh_slice * h^T  (contiguous packed frag stream, L2)
        #pragma unroll 2
        for (int kt = 0; kt < 8; ++kt) {
            // zero-conflict h read: byte = kt*1024 + ln*16
            bf16x8 b0 = *(const bf16x8*)(hRd + kt * 1024 + ln * 16);
            #pragma unroll
            for (int g = 0; g < 4; ++g) {
                bf16x8 a = *(const bf16x8*)(wbase + (size_t)(kt * 4 + g) * 512);
                acc[g] = __builtin_amdgcn_mfma_f32_16x16x32_bf16(a, b0, acc[g], 0, 0, 0);
            }
        }

        // issue next step's DMAs into the OTHER pstage buffer (no lgkm
        // guard needed: dest differs from the buffer being read this step)
        if (t + 1 < maxlen) {
            __builtin_amdgcn_sched_barrier(0);
            #pragma unroll
            for (int d = 0; d < 2; ++d) {
                const unsigned short* src = P + (size_t)tknext * 2048 + pco +
                    (2 * d + dg) * 256 + wv * 16 + dh * 8;
                gld_lds16(src, &pstage[pb ^ 1][wv][2 * d][0][0][0]);
            }
            int t2 = (t + 2 < T) ? (t + 2) : (T - 1);
            tknext = tok[(s0 + l15) * T + t2];
        }

        // activation + h write to the other buffer (frozen lanes rewrite hpk)
        {
            bool act = t < len0;
            if (act) {
                float hr[4];
                #pragma unroll
                for (int r = 0; r < 4; ++r) {
                    float iv = acc[0][r];
                    float fv = acc[1][r];
                    float gv = acc[2][r];
                    float ov = acc[3][r];
                    float cn = sigm(fv) * c[r] + sigm(iv) * tanh_(gv);
                    c[r] = cn;
                    hr[r] = sigm(ov) * tanh_(cn);
                }
                hpk = make_ushort4(f2bf(hr[0]), f2bf(hr[1]),
                                   f2bf(hr[2]), f2bf(hr[3]));
            }
            *(ushort4*)(hWr + wrByte) = hpk;
        }
        // ONE barrier per step: h writes visible before next step's reads
        asm volatile("s_waitcnt lgkmcnt(0)\n\ts_barrier" ::: "memory");
    }

    // fused segment-sum epilogue: h -> atomicAdd into seg[part]
    const char* hF = (maxlen & 1) ? hB1 : hB0;
    for (int i = tid; i < 16 * HIDN; i += 1024) {
        int sq = i >> 8, hd = i & 255;
        unsigned short hv = *(const unsigned short*)
            (hF + (hd >> 5) * 1024 + ((hd >> 3) & 3) * 256 +
             sq * 16 + (hd & 7) * 2);
        int rf = refs[s0 + sq];
        atomicAdd(segp + (size_t)rf * 256 + hd, bf2f(hv));
    }
}

// ------------------------------------------------------------------ loss
__global__ void loss_kernel(const float* __restrict__ seg, float* __restrict__ part)
{
    int d = blockIdx.x, tid = threadIdx.x;
    const float* sc = seg + (size_t)d * 256;
    const float* sr = seg + 1048576 + (size_t)d * 256;
    const float* sn = seg + 2097152 + (size_t)d * 256;
    float a = sc[tid];
    float p = a * sr[tid];
    float n = a * sn[tid];
    for (int off = 32; off; off >>= 1) { p += __shfl_down(p, off); n += __shfl_down(n, off); }
    __shared__ float rp[4], rn[4];
    if ((tid & 63) == 0) { rp[tid >> 6] = p; rn[tid >> 6] = n; }
    __syncthreads();
    if (tid == 0) {
        float Ps = rp[0] + rp[1] + rp[2] + rp[3];
        float Ns = rn[0] + rn[1] + rn[2] + rn[3];
        float x = Ps - Ns;
        part[d] = fmaxf(-x, 0.f) + log1pf(expf(-fabsf(x)));  // softplus(-x)
    }
}

__global__ void reduce_kernel(const float* __restrict__ part, float* __restrict__ out)
{
    int tid = threadIdx.x;
    float s = 0.f;
    for (int i = tid; i < 4096; i += 256) s += part[i];
    for (int off = 32; off; off >>= 1) s += __shfl_down(s, off);
    __shared__ float r[4];
    if ((tid & 63) == 0) r[tid >> 6] = s;
    __syncthreads();
    if (tid == 0) out[0] = r[0] + r[1] + r[2] + r[3];
}

// ---------------------------------------------------------------------------
extern "C" void kernel_launch(void* const* d_in, const int* in_sizes, int n_in,
                              void* d_out, int out_size, void* d_ws, size_t ws_size,
                              hipStream_t stream)
{
    const int*   col      = (const int*)d_in[0];
    const int*   row      = (const int*)d_in[1];
    const int*   rneg     = (const int*)d_in[2];
    const int*   col_lens = (const int*)d_in[3];
    const int*   row_lens = (const int*)d_in[4];
    const int*   rng_lens = (const int*)d_in[5];
    const int*   col_refs = (const int*)d_in[6];
    const int*   row_refs = (const int*)d_in[7];
    const int*   rng_refs = (const int*)d_in[8];
    const float* embed    = (const float*)d_in[9];
    const float* cWih     = (const float*)d_in[10];
    const float* cWhh     = (const float*)d_in[11];
    const float* cbih     = (const float*)d_in[12];
    const float* cbhh     = (const float*)d_in[13];
    const float* rWih     = (const float*)d_in[14];
    const float* rWhh     = (const float*)d_in[15];
    const float* rbih     = (const float*)d_in[16];
    const float* rbhh     = (const float*)d_in[17];

    char* ws = (char*)d_ws;
    unsigned short* P    = (unsigned short*)(ws + OFF_P);
    unsigned short* Bpk  = (unsigned short*)(ws + OFF_BPK);
    unsigned short* WhhC = (unsigned short*)(ws + OFF_WHHC);
    unsigned short* WhhR = (unsigned short*)(ws + OFF_WHHR);
    float* biascat = (float*)(ws + OFF_BIAS);
    float* seg     = (float*)(ws + OFF_SEG);
    float* lpart   = (float*)(ws + OFF_LOSS);

    hipMemsetAsync(seg, 0, 3 * 4096 * 256 * sizeof(float), stream);

    prep_kernel<<<4616, 256, 0, stream>>>(cWih, rWih, cWhh, rWhh,
                                          cbih, cbhh, rbih, rbhh,
                                          Bpk, WhhC, WhhR, biascat);
    gemm_p_kernel<<<391, 256, 0, stream>>>(embed, Bpk, biascat, P);
    lstm_kernel<<<768, 1024, 0, stream>>>(col, row, rneg,
                                          col_lens, row_lens, rng_lens,
                                          col_refs, row_refs, rng_refs,
                                          P, WhhC, WhhR, seg);
    loss_kernel<<<4096, 256, 0, stream>>>(seg, lpart);
    reduce_kernel<<<1, 256, 0, stream>>>(lpart, (float*)d_out);
}

// Round 12
// 601.401 us; speedup vs baseline: 2.3763x; 1.1465x over previous
//
#include <hip/hip_runtime.h>

// ---------------------------------------------------------------------------
// NaryCompUSchema: embed -> 3x masked LSTM (last hidden) -> segment_sum -> BPR
//   P[v, 0:1024]   = embed[v] @ col_W_ih^T + (col_b_ih + col_b_hh)   (bf16)
//   P[v,1024:2048] = embed[v] @ row_W_ih^T + (row_b_ih + row_b_hh)
//   Recurrence: gates^T = W_hh * h^T via mfma_f32_16x16x32_bf16.
// R12 (R11 null result: solo block == shared block tau -> NOT port-bound;
// latency-bound on the W-load serial chain, VGPR=36 = ~3 loads in flight):
//   - RESIDENT W HALF: kt0-3's 16 frags (64 VGPR) loaded once pre-loop.
//     Step opens with 16 register-fed MFMAs covering the streamed kt4-7
//     half (16 loads, was 32 exposed).
//   - P-add moved POST-kt-loop: acc 0-init, MFMAs start immediately;
//     vmcnt(0) for the P gather sits after ~2k cy of compute. pstage
//     single-buffered (32KB), post-consumption lgkm guard.
//   - LDS 48KB (R11's 1-block/CU pad bought nothing; revert).
// ---------------------------------------------------------------------------

typedef __bf16 bf16x8 __attribute__((ext_vector_type(8)));
typedef float  fvec4  __attribute__((ext_vector_type(4)));

#define NSEN 4096
#define HIDN 256
#define EMBD 300
#define VOC  50000

// workspace layout (bytes)
#define OFF_P     0ULL            // ushort [50000][2048]
#define OFF_BPK   204800000ULL    // ushort [16][2][10][4][512]  (packed W_ih)
#define OFF_WHHC  206110720ULL    // ushort [262144]      (packed frag order)
#define OFF_WHHR  206635008ULL    // ushort [262144]      (packed frag order)
#define OFF_BIAS  207159296ULL    // float  [2048]
#define OFF_SEG   219750400ULL    // float  [3][4096][256]
#define OFF_LOSS  232333312ULL    // float  [4096]

static __device__ __forceinline__ unsigned short f2bf(float x) {
    unsigned int u = __float_as_uint(x);
    unsigned int r = (u + 0x7fffu + ((u >> 16) & 1u)) >> 16;  // RNE
    return (unsigned short)r;
}
static __device__ __forceinline__ float bf2f(unsigned short b) {
    return __uint_as_float(((unsigned int)b) << 16);
}
static __device__ __forceinline__ float sigm(float x) { return 1.f / (1.f + __expf(-x)); }
static __device__ __forceinline__ float tanh_(float x) {
    float e = __expf(2.f * x);
    return 1.f - 2.f / (e + 1.f);   // stable at +-inf
}
static __device__ __forceinline__ fvec4 unpk(uint2 v) {
    fvec4 o;
    o[0] = __uint_as_float((v.x & 0xffffu) << 16);
    o[1] = __uint_as_float(v.x & 0xffff0000u);
    o[2] = __uint_as_float((v.y & 0xffffu) << 16);
    o[3] = __uint_as_float(v.y & 0xffff0000u);
    return o;
}

// async 16B/lane gather into wave-private LDS (lane-ordered linear dest)
static __device__ __forceinline__ void gld_lds16(const unsigned short* g,
                                                 unsigned short* l)
{
    __builtin_amdgcn_global_load_lds(
        (const __attribute__((address_space(1))) unsigned int*)g,
        (__attribute__((address_space(3))) unsigned int*)l, 16, 0, 0);
}

// Whh packed layout (16-wave): frag L = (wv<<5)|(kt<<2)|g, elem = L*512+ln*8+j
// lane ln holds Whh[row][col], row = g*256 + wv*16 + (ln&15),
//                              col = kt*32 + (ln>>4)*8 + j
static __device__ __forceinline__ int whh_src(int o) {
    int L  = o >> 9;
    int r9 = o & 511;
    int ln = r9 >> 3, j = r9 & 7;
    int g  = L & 3, kt = (L >> 2) & 7, wv = (L >> 5) & 15;
    int row = g * 256 + wv * 16 + (ln & 15);
    int col = kt * 32 + (ln >> 4) * 8 + j;
    return row * 256 + col;
}

// ---------------------------------------------------------------- prep: pack
__global__ void prep_kernel(
    const float* __restrict__ cWih, const float* __restrict__ rWih,
    const float* __restrict__ cWhh, const float* __restrict__ rWhh,
    const float* __restrict__ cbih, const float* __restrict__ cbhh,
    const float* __restrict__ rbih, const float* __restrict__ rbhh,
    unsigned short* __restrict__ Bpk, unsigned short* __restrict__ WhhC,
    unsigned short* __restrict__ WhhR, float* __restrict__ biascat)
{
    int idx = blockIdx.x * 256 + threadIdx.x;
    if (idx < 655360) {
        // Bpk: frag f = ((nc*2+wn)*10 + kt)*4 + ntt, elem e = ln*8 + j
        int e = idx & 511, lnn = e >> 3, j = e & 7;
        int f = idx >> 9;
        int ntt = f & 3;
        int kc = f >> 2;            // (nc*2+wn)*10 + kt
        int kt = kc % 10;
        int s  = kc / 10;           // nc*2 + wn
        int n = (s >> 1) * 128 + (s & 1) * 64 + ntt * 16 + (lnn & 15);
        int k = kt * 32 + (lnn >> 4) * 8 + j;
        float v = 0.f;
        if (k < EMBD) v = (n < 1024) ? cWih[n * EMBD + k] : rWih[(n - 1024) * EMBD + k];
        Bpk[idx] = f2bf(v);
        return;
    }
    idx -= 655360;
    if (idx < 262144) { WhhC[idx] = f2bf(cWhh[whh_src(idx)]); return; }
    idx -= 262144;
    if (idx < 262144) { WhhR[idx] = f2bf(rWhh[whh_src(idx)]); return; }
    idx -= 262144;
    if (idx < 2048)
        biascat[idx] = (idx < 1024) ? (cbih[idx] + cbhh[idx])
                                    : (rbih[idx - 1024] + rbhh[idx - 1024]);
}

// ------------------------------------------------------- P = embed @ Wcat^T
// v3: grid 391; block owns 128 M-rows x full N=2048. A staged once in LDS.
__global__ __launch_bounds__(256) void gemm_p_kernel(
    const float* __restrict__ A,          // embed [50000][300] fp32
    const unsigned short* __restrict__ Bpk,
    const float* __restrict__ bias,       // [2048]
    unsigned short* __restrict__ Pout)    // [50000][2048] bf16
{
    const int mb = blockIdx.x * 128;
    const int tid = threadIdx.x;
    const int wv = tid >> 6, ln = tid & 63, l15 = ln & 15, q = ln >> 4;
    const int wm = wv & 1, wn = wv >> 1;

    // A frags: At[wm][mt][kt][512], elem = ln*8+j ; value A[row][k],
    // row = wm*64+mt*16+(ln&15), k = kt*32+(ln>>4)*8+j   (80 KB)
    __shared__ __align__(16) unsigned short At[2][4][10][512];

    {   // stage: thread t covers row = t>>1, k in [ (t&1)*160, +160 )
        int row = tid >> 1, kh = tid & 1;
        int gr = mb + row;
        unsigned short* dst = &At[row >> 6][(row >> 4) & 3][0][0];
        const int fl = row & 15;
        #pragma unroll
        for (int i = 0; i < 40; ++i) {
            int k = kh * 160 + i * 4;
            float4 v = make_float4(0.f, 0.f, 0.f, 0.f);
            if (gr < VOC && k < EMBD)
                v = *(const float4*)(A + (size_t)gr * EMBD + k);
            ushort4 b;
            b.x = f2bf(v.x); b.y = f2bf(v.y); b.z = f2bf(v.z); b.w = f2bf(v.w);
            int di = (k >> 5) * 512 + ((k >> 3) & 3) * 128 + fl * 8 + (k & 7);
            *(ushort4*)(dst + di) = b;
        }
    }
    __syncthreads();

    for (int nc = 0; nc < 16; ++nc) {
        fvec4 acc[4][4];
        #pragma unroll
        for (int a = 0; a < 4; ++a)
            #pragma unroll
            for (int b = 0; b < 4; ++b) acc[a][b] = (fvec4)0.f;

        #pragma unroll 2
        for (int kt = 0; kt < 10; ++kt) {
            const unsigned short* bp =
                Bpk + (size_t)(((nc * 2 + wn) * 10 + kt) * 4) * 512 + ln * 8;
            bf16x8 bfr[4];
            #pragma unroll
            for (int ntt = 0; ntt < 4; ++ntt)
                bfr[ntt] = *(const bf16x8*)(bp + ntt * 512);
            #pragma unroll
            for (int mt = 0; mt < 4; ++mt) {
                bf16x8 af = *(const bf16x8*)&At[wm][mt][kt][ln * 8];
                #pragma unroll
                for (int ntt = 0; ntt < 4; ++ntt)
                    acc[mt][ntt] = __builtin_amdgcn_mfma_f32_16x16x32_bf16(
                        af, bfr[ntt], acc[mt][ntt], 0, 0, 0);
            }
        }
        float bv[4];
        #pragma unroll
        for (int ntt = 0; ntt < 4; ++ntt)
            bv[ntt] = bias[nc * 128 + wn * 64 + ntt * 16 + l15];
        #pragma unroll
        for (int mt = 0; mt < 4; ++mt) {
            #pragma unroll
            for (int r = 0; r < 4; ++r) {
                int m = mb + wm * 64 + mt * 16 + q * 4 + r;
                if (m < VOC) {
                    size_t base = (size_t)m * 2048 + nc * 128 + wn * 64;
                    #pragma unroll
                    for (int ntt = 0; ntt < 4; ++ntt)
                        Pout[base + ntt * 16 + l15] = f2bf(acc[mt][ntt][r] + bv[ntt]);
                }
            }
        }
    }
}

// ----------------------------------------------------------------- LSTMs
// grid 768 x 1024: blocks [0,256) col, [256,512) row, [512,768) row_neg.
// Block: 16 seqs, 16 waves; wave wv owns hidden units [16wv, 16wv+16).
// kt0-3 W frags register-resident (loaded once); kt4-7 streamed from L2.
// acc 0-init; P added post-kt-loop (gather latency hidden under MFMAs).
__global__ __launch_bounds__(1024, 2) void lstm_kernel(
    const int* __restrict__ colTok, const int* __restrict__ rowTok, const int* __restrict__ negTok,
    const int* __restrict__ colLen, const int* __restrict__ rowLen, const int* __restrict__ negLen,
    const int* __restrict__ crefs, const int* __restrict__ rrefs, const int* __restrict__ nrefs,
    const unsigned short* __restrict__ P,
    const unsigned short* __restrict__ WhhC, const unsigned short* __restrict__ WhhR,
    float* __restrict__ seg)
{
    const int part = blockIdx.x >> 8;
    const int sb = blockIdx.x & 255;
    const int s0 = sb * 16;
    const int* tok = part == 0 ? colTok : (part == 1 ? rowTok : negTok);
    const int* len = part == 0 ? colLen : (part == 1 ? rowLen : negLen);
    const int* refs = part == 0 ? crefs : (part == 1 ? rrefs : nrefs);
    const unsigned short* Whh = part == 0 ? WhhC : WhhR;
    const int T = part == 0 ? 64 : 16;
    const int pco = part == 0 ? 0 : 1024;
    float* segp = seg + (size_t)part * 1048576;

    const int tid = threadIdx.x;
    const int wv = tid >> 6;            // 0..15
    const int ln = tid & 63, l15 = ln & 15, q = ln >> 4;

    __shared__ __align__(16) unsigned short hx[2][8][4][16][8];       // 16 KB
    __shared__ __align__(16) unsigned short pstage[16][4][2][16][8];  // 32 KB
    char* hB0 = (char*)&hx[0][0][0][0][0];
    char* hB1 = (char*)&hx[1][0][0][0][0];

    for (int i = tid; i < 8192; i += 1024) (&hx[0][0][0][0][0])[i] = 0;

    // lens in regs: per-lane load + shfl-xor max over the 16 seqs
    const int len0 = len[s0 + l15];
    int ml = len0;
    #pragma unroll
    for (int off = 1; off < 16; off <<= 1) ml = max(ml, __shfl_xor(ml, off));
    const int maxlen = ml;

    // per-wave contiguous packed-Whh stream base (32 KB per wave per step)
    const unsigned short* wbase = Whh + (size_t)wv * 16384 + (size_t)ln * 8;

    // h write byte: unit u = wv*16 + q*4 + r -> kt = wv>>1,
    // qc = (wv&1)*2 + (q>>1), j = (q&1)*4 + r ; seq = l15
    const int wrByte = (wv >> 1) * 1024 + ((wv & 1) * 2 + (q >> 1)) * 256 +
                       l15 * 16 + (q & 1) * 8;

    // DMA lane mapping: instr d stages gates 2d,2d+1 (1KB, dest lane-linear):
    // lane ln -> gate = 2d + (ln>>5), half = (ln>>4)&1, seq = ln&15
    const int dg = ln >> 5, dh = (ln >> 4) & 1;

    float c[4];
    #pragma unroll
    for (int r = 0; r < 4; ++r) c[r] = 0.f;
    ushort4 hpk = make_ushort4(0, 0, 0, 0);

    // ---- resident W half: kt 0..3, loaded ONCE (16 frags = 64 VGPR)
    bf16x8 wres[4][4];
    #pragma unroll
    for (int kt = 0; kt < 4; ++kt)
        #pragma unroll
        for (int g = 0; g < 4; ++g)
            wres[kt][g] = *(const bf16x8*)(wbase + (size_t)(kt * 4 + g) * 512);

    __syncthreads();   // hx zero-init visible

    // ---- prologue: DMA-stage P rows for t=0
    {
        int tk = tok[(s0 + l15) * T];
        #pragma unroll
        for (int d = 0; d < 2; ++d) {
            const unsigned short* src = P + (size_t)tk * 2048 + pco +
                (2 * d + dg) * 256 + wv * 16 + dh * 8;
            gld_lds16(src, &pstage[wv][2 * d][0][0][0]);
        }
    }
    int tknext = tok[(s0 + l15) * T + 1];   // T >= 16

    for (int t = 0; t < maxlen; ++t) {
        const char* hRd = (t & 1) ? hB1 : hB0;
        char* hWr = (t & 1) ? hB0 : hB1;

        // acc 0-init: MFMAs start immediately, no VMEM dependency
        fvec4 acc[4];
        #pragma unroll
        for (int g = 0; g < 4; ++g) acc[g] = (fvec4)0.f;

        // resident half (register-fed; covers streamed-half load latency)
        #pragma unroll
        for (int kt = 0; kt < 4; ++kt) {
            bf16x8 b0 = *(const bf16x8*)(hRd + kt * 1024 + ln * 16);
            #pragma unroll
            for (int g = 0; g < 4; ++g)
                acc[g] = __builtin_amdgcn_mfma_f32_16x16x32_bf16(
                    wres[kt][g], b0, acc[g], 0, 0, 0);
        }
        // streamed half (16 L2 loads, compiler-scheduled)
        #pragma unroll 2
        for (int kt = 4; kt < 8; ++kt) {
            bf16x8 b0 = *(const bf16x8*)(hRd + kt * 1024 + ln * 16);
            #pragma unroll
            for (int g = 0; g < 4; ++g) {
                bf16x8 a = *(const bf16x8*)(wbase + (size_t)(kt * 4 + g) * 512);
                acc[g] = __builtin_amdgcn_mfma_f32_16x16x32_bf16(a, b0, acc[g], 0, 0, 0);
            }
        }

        // P contribution: the t-gather had the whole kt loop to land
        asm volatile("s_waitcnt vmcnt(0)" ::: "memory");
        #pragma unroll
        for (int g = 0; g < 4; ++g) {
            fvec4 pv = unpk(*(const uint2*)
                &pstage[wv][g][q >> 1][l15][(q & 1) * 4]);
            acc[g] += pv;
        }

        // issue next step's DMAs (single pstage buffer; reads just drained)
        if (t + 1 < maxlen) {
            asm volatile("s_waitcnt lgkmcnt(0)" ::: "memory");
            __builtin_amdgcn_sched_barrier(0);
            #pragma unroll
            for (int d = 0; d < 2; ++d) {
                const unsigned short* src = P + (size_t)tknext * 2048 + pco +
                    (2 * d + dg) * 256 + wv * 16 + dh * 8;
                gld_lds16(src, &pstage[wv][2 * d][0][0][0]);
            }
            int t2 = (t + 2 < T) ? (t + 2) : (T - 1);
            tknext = tok[(s0 + l15) * T + t2];
        }

        // activation + h write to the other buffer (frozen lanes rewrite hpk)
        {
            bool act = t < len0;
            if (act) {
                float hr[4];
                #pragma unroll
                for (int r = 0; r < 4; ++r) {
                    float iv = acc[0][r];
                    float fv = acc[1][r];
                    float gv = acc[2][r];
                    float ov = acc[3][r];
                    float cn = sigm(fv) * c[r] + sigm(iv) * tanh_(gv);
                    c[r] = cn;
                    hr[r] = sigm(ov) * tanh_(cn);
                }
                hpk = make_ushort4(f2bf(hr[0]), f2bf(hr[1]),
                                   f2bf(hr[2]), f2bf(hr[3]));
            }
            *(ushort4*)(hWr + wrByte) = hpk;
        }
        // ONE barrier per step: h writes visible before next step's reads
        asm volatile("s_waitcnt lgkmcnt(0)\n\ts_barrier" ::: "memory");
    }

    // fused segment-sum epilogue: h -> atomicAdd into seg[part]
    const char* hF = (maxlen & 1) ? hB1 : hB0;
    for (int i = tid; i < 16 * HIDN; i += 1024) {
        int sq = i >> 8, hd = i & 255;
        unsigned short hv = *(const unsigned short*)
            (hF + (hd >> 5) * 1024 + ((hd >> 3) & 3) * 256 +
             sq * 16 + (hd & 7) * 2);
        int rf = refs[s0 + sq];
        atomicAdd(segp + (size_t)rf * 256 + hd, bf2f(hv));
    }
}

// ------------------------------------------------------------------ loss
__global__ void loss_kernel(const float* __restrict__ seg, float* __restrict__ part)
{
    int d = blockIdx.x, tid = threadIdx.x;
    const float* sc = seg + (size_t)d * 256;
    const float* sr = seg + 1048576 + (size_t)d * 256;
    const float* sn = seg + 2097152 + (size_t)d * 256;
    float a = sc[tid];
    float p = a * sr[tid];
    float n = a * sn[tid];
    for (int off = 32; off; off >>= 1) { p += __shfl_down(p, off); n += __shfl_down(n, off); }
    __shared__ float rp[4], rn[4];
    if ((tid & 63) == 0) { rp[tid >> 6] = p; rn[tid >> 6] = n; }
    __syncthreads();
    if (tid == 0) {
        float Ps = rp[0] + rp[1] + rp[2] + rp[3];
        float Ns = rn[0] + rn[1] + rn[2] + rn[3];
        float x = Ps - Ns;
        part[d] = fmaxf(-x, 0.f) + log1pf(expf(-fabsf(x)));  // softplus(-x)
    }
}

__global__ void reduce_kernel(const float* __restrict__ part, float* __restrict__ out)
{
    int tid = threadIdx.x;
    float s = 0.f;
    for (int i = tid; i < 4096; i += 256) s += part[i];
    for (int off = 32; off; off >>= 1) s += __shfl_down(s, off);
    __shared__ float r[4];
    if ((tid & 63) == 0) r[tid >> 6] = s;
    __syncthreads();
    if (tid == 0) out[0] = r[0] + r[1] + r[2] + r[3];
}

// ---------------------------------------------------------------------------
extern "C" void kernel_launch(void* const* d_in, const int* in_sizes, int n_in,
                              void* d_out, int out_size, void* d_ws, size_t ws_size,
                              hipStream_t stream)
{
    const int*   col      = (const int*)d_in[0];
    const int*   row      = (const int*)d_in[1];
    const int*   rneg     = (const int*)d_in[2];
    const int*   col_lens = (const int*)d_in[3];
    const int*   row_lens = (const int*)d_in[4];
    const int*   rng_lens = (const int*)d_in[5];
    const int*   col_refs = (const int*)d_in[6];
    const int*   row_refs = (const int*)d_in[7];
    const int*   rng_refs = (const int*)d_in[8];
    const float* embed    = (const float*)d_in[9];
    const float* cWih     = (const float*)d_in[10];
    const float* cWhh     = (const float*)d_in[11];
    const float* cbih     = (const float*)d_in[12];
    const float* cbhh     = (const float*)d_in[13];
    const float* rWih     = (const float*)d_in[14];
    const float* rWhh     = (const float*)d_in[15];
    const float* rbih     = (const float*)d_in[16];
    const float* rbhh     = (const float*)d_in[17];

    char* ws = (char*)d_ws;
    unsigned short* P    = (unsigned short*)(ws + OFF_P);
    unsigned short* Bpk  = (unsigned short*)(ws + OFF_BPK);
    unsigned short* WhhC = (unsigned short*)(ws + OFF_WHHC);
    unsigned short* WhhR = (unsigned short*)(ws + OFF_WHHR);
    float* biascat = (float*)(ws + OFF_BIAS);
    float* seg     = (float*)(ws + OFF_SEG);
    float* lpart   = (float*)(ws + OFF_LOSS);

    hipMemsetAsync(seg, 0, 3 * 4096 * 256 * sizeof(float), stream);

    prep_kernel<<<4616, 256, 0, stream>>>(cWih, rWih, cWhh, rWhh,
                                          cbih, cbhh, rbih, rbhh,
                                          Bpk, WhhC, WhhR, biascat);
    gemm_p_kernel<<<391, 256, 0, stream>>>(embed, Bpk, biascat, P);
    lstm_kernel<<<768, 1024, 0, stream>>>(col, row, rneg,
                                          col_lens, row_lens, rng_lens,
                                          col_refs, row_refs, rng_refs,
                                          P, WhhC, WhhR, seg);
    loss_kernel<<<4096, 256, 0, stream>>>(seg, lpart);
    reduce_kernel<<<1, 256, 0, stream>>>(lpart, (float*)d_out);
}